// Round 2
// baseline (2872.712 us; speedup 1.0000x reference)
//
#include <hip/hip_runtime.h>
#include <math.h>

#define Bb 2
#define Tt 1024
#define Ss 1024
#define Dd 512
#define Hh 8
#define Ll 4
#define Ee 8
#define FFf 2048
#define Mm 2048
#define NPp 4096
#define EPSF 1e-5f
#define DD_ (Dd*Dd)
#define LOSC 1024.0f
#define ILOSC (1.0f/1024.0f)
#define RBLK 64   // router blocks (Mm/32)
#define IMm (1.0f/(float)Mm)

typedef _Float16 f16;
typedef __attribute__((ext_vector_type(8))) _Float16 f16x8;
typedef __attribute__((ext_vector_type(4))) _Float16 f16x4;
typedef __attribute__((ext_vector_type(4))) float f32x4;

// split: x = hi + lo/1024 (lo pre-scaled by 1024 so it stays fp16-normal)
__device__ __forceinline__ void fsplit(float x, f16& h, f16& l) {
  h = (f16)x;
  l = (f16)((x - (float)h) * LOSC);
}

__device__ __forceinline__ void load16(const void* g, void* l) {
  __builtin_amdgcn_global_load_lds(
      (const __attribute__((address_space(1))) void*)g,
      (__attribute__((address_space(3))) void*)l, 16, 0, 0);
}

// ---------------------------------------------------------------------------
__global__ void embed_kernel(const int* __restrict__ ids,
                             const float* __restrict__ emb,
                             const float* __restrict__ pos,
                             float* __restrict__ Y,
                             f16* __restrict__ Yh, f16* __restrict__ Yl) {
  int m = blockIdx.x;
  int t = m % Tt;
  int id = ids[m];
  for (int d = threadIdx.x; d < Dd; d += 256) {
    float v = emb[(size_t)id * Dd + d] + pos[(size_t)t * Dd + d];
    Y[(size_t)m * Dd + d] = v;
    f16 h, l; fsplit(v, h, l);
    Yh[(size_t)m * Dd + d] = h;
    Yl[(size_t)m * Dd + d] = l;
  }
}

__global__ void cvt_split_kernel(const float* __restrict__ src,
                                 f16* __restrict__ dh, f16* __restrict__ dl) {
  size_t i = ((size_t)blockIdx.x * 256 + threadIdx.x) * 4;
  float4 v = *reinterpret_cast<const float4*>(&src[i]);
  float a[4] = {v.x, v.y, v.z, v.w};
#pragma unroll
  for (int j = 0; j < 4; j++) { f16 h, l; fsplit(a[j], h, l); dh[i + j] = h; dl[i + j] = l; }
}

__global__ void zero_kernel(float* __restrict__ p) {
  size_t i = ((size_t)blockIdx.x * 256 + threadIdx.x) * 4;
  *reinterpret_cast<float4*>(&p[i]) = make_float4(0.f, 0.f, 0.f, 0.f);
}

// ---------------------------------------------------------------------------
// Batched transpose+split: src[z]=[Kd,Nd] fp32 -> dstH/dstL[z]=[Nd,Kd] fp16
// ---------------------------------------------------------------------------
__global__ __launch_bounds__(256)
void transpose_split(const float* __restrict__ src,
                     f16* __restrict__ dstH, f16* __restrict__ dstL,
                     int Kd, int Nd) {
  __shared__ float Tl[32][33];
  size_t zo = (size_t)blockIdx.z * Kd * Nd;
  int k0 = blockIdx.y * 32, n0 = blockIdx.x * 32;
  int t = threadIdx.x;
  int r = t >> 3, c = t & 7;
  float4 v = *reinterpret_cast<const float4*>(&src[zo + (size_t)(k0 + r) * Nd + n0 + c * 4]);
  Tl[r][c * 4 + 0] = v.x; Tl[r][c * 4 + 1] = v.y;
  Tl[r][c * 4 + 2] = v.z; Tl[r][c * 4 + 3] = v.w;
  __syncthreads();
  int nl = t >> 3, kq = t & 7;
  f16x4 hv, lv;
#pragma unroll
  for (int i = 0; i < 4; i++) {
    f16 h, l; fsplit(Tl[kq * 4 + i][nl], h, l);
    hv[i] = h; lv[i] = l;
  }
  size_t o = zo + (size_t)(n0 + nl) * Kd + k0 + kq * 4;
  *reinterpret_cast<f16x4*>(&dstH[o]) = hv;
  *reinterpret_cast<f16x4*>(&dstL[o]) = lv;
}

// ---------------------------------------------------------------------------
// 128x128 split-fp16 MFMA GEMM (3-product). A hi/lo [*,K], B hi/lo [N,K].
// KS>1: split-K over blockIdx.z (z = expert*KS + kslice); partials are
// atomicAdd'ed into pre-zeroed Cf (bias applied in slice 0; gate distributes).
// LDS slot-XOR swizzle: linear global_load_lds dest, pre-swizzled global
// source slot (cc ^ ((rr>>1)&3)), swizzled ds_read slot (quad ^ ((m16>>1)&3)).
// ---------------------------------------------------------------------------
template <bool GATHER, bool OSPLIT, bool RELU, bool GATE, int KS>
__global__ __launch_bounds__(256)
void mm128(const f16* __restrict__ Ah_, const f16* __restrict__ Al_, int lda,
           const f16* __restrict__ Bh_, const f16* __restrict__ Bl_,
           const float* __restrict__ bias,
           float* __restrict__ Cf, f16* __restrict__ Ch, f16* __restrict__ Cl, int ldc,
           int Mtot, int N, int K,
           const int* __restrict__ tok, const float* __restrict__ gate,
           const int* __restrict__ offs, const int* __restrict__ cnt) {
  __shared__ f16 Ash[128 * 32];
  __shared__ f16 Asl[128 * 32];
  __shared__ f16 Bsh[128 * 32];
  __shared__ f16 Bsl[128 * 32];
  int zz = blockIdx.z;
  int e  = (KS > 1) ? (zz / KS) : zz;
  int ks = (KS > 1) ? (zz % KS) : 0;
  int base = 0, ne = Mtot;
  if (offs) { base = offs[e]; ne = cnt[e]; }
  int m0 = blockIdx.y * 128;
  if (m0 >= ne) return;
  int rem = ne - m0;
  Bh_ += (size_t)e * N * K;
  Bl_ += (size_t)e * N * K;
  bias += (size_t)e * N;

  int t = threadIdx.x;
  int rr = t >> 2, cc = t & 3;
  int csw = cc ^ ((rr >> 1) & 3);   // pre-swizzled source slot
  int gr0 = base + m0 + rr;      if (gr0 > Mtot - 1) gr0 = Mtot - 1;
  int gr1 = base + m0 + rr + 64; if (gr1 > Mtot - 1) gr1 = Mtot - 1;
  int arow0 = GATHER ? tok[gr0] : gr0;
  int arow1 = GATHER ? tok[gr1] : gr1;
  size_t aoff0 = (size_t)arow0 * lda + csw * 8;
  size_t aoff1 = (size_t)arow1 * lda + csw * 8;
  size_t boff0 = (size_t)(blockIdx.x * 128 + rr) * K + csw * 8;
  size_t boff1 = (size_t)(blockIdx.x * 128 + rr + 64) * K + csw * 8;

  int lane = t & 63, wv = t >> 6;
  int quad = lane >> 4, m16 = lane & 15;
  int sw = quad ^ ((m16 >> 1) & 3);  // swizzled read slot
  int wm = (wv >> 1) * 64, wn = (wv & 1) * 64;

  f32x4 accm[4][4], accc[4][4];
#pragma unroll
  for (int i = 0; i < 4; i++)
#pragma unroll
    for (int j = 0; j < 4; j++) {
      accm[i][j] = (f32x4){0.f, 0.f, 0.f, 0.f};
      accc[i][j] = (f32x4){0.f, 0.f, 0.f, 0.f};
    }

  int kper = K / KS;
  int kbeg = ks * kper;
  for (int kc = kbeg; kc < kbeg + kper; kc += 32) {
    load16(Ah_ + aoff0 + kc, &Ash[t * 8]);
    load16(Ah_ + aoff1 + kc, &Ash[2048 + t * 8]);
    load16(Al_ + aoff0 + kc, &Asl[t * 8]);
    load16(Al_ + aoff1 + kc, &Asl[2048 + t * 8]);
    load16(Bh_ + boff0 + kc, &Bsh[t * 8]);
    load16(Bh_ + boff1 + kc, &Bsh[2048 + t * 8]);
    load16(Bl_ + boff0 + kc, &Bsl[t * 8]);
    load16(Bl_ + boff1 + kc, &Bsl[2048 + t * 8]);
    __syncthreads();
    f16x8 ah[4], al[4];
#pragma unroll
    for (int i = 0; i < 4; i++) {
      ah[i] = *reinterpret_cast<const f16x8*>(&Ash[(wm + i * 16 + m16) * 32 + sw * 8]);
      al[i] = *reinterpret_cast<const f16x8*>(&Asl[(wm + i * 16 + m16) * 32 + sw * 8]);
    }
#pragma unroll
    for (int j = 0; j < 4; j++) {
      f16x8 bh = *reinterpret_cast<const f16x8*>(&Bsh[(wn + j * 16 + m16) * 32 + sw * 8]);
      f16x8 bl = *reinterpret_cast<const f16x8*>(&Bsl[(wn + j * 16 + m16) * 32 + sw * 8]);
#pragma unroll
      for (int i = 0; i < 4; i++) {
        accm[i][j] = __builtin_amdgcn_mfma_f32_16x16x32_f16(ah[i], bh, accm[i][j], 0, 0, 0);
        accc[i][j] = __builtin_amdgcn_mfma_f32_16x16x32_f16(ah[i], bl, accc[i][j], 0, 0, 0);
        accc[i][j] = __builtin_amdgcn_mfma_f32_16x16x32_f16(al[i], bh, accc[i][j], 0, 0, 0);
      }
    }
    __syncthreads();
  }

#pragma unroll
  for (int i = 0; i < 4; i++) {
#pragma unroll
    for (int reg = 0; reg < 4; reg++) {
      int lr = wm + i * 16 + quad * 4 + reg;
      if (lr < rem) {
        size_t grow = (size_t)(base + m0 + lr);
        float gv = 1.f;
        if (GATE) gv = gate[grow];
#pragma unroll
        for (int j = 0; j < 4; j++) {
          int col = blockIdx.x * 128 + wn + j * 16 + m16;
          float bv = (KS == 1 || ks == 0) ? bias[col] : 0.f;
          float v = accm[i][j][reg] + accc[i][j][reg] * ILOSC + bv;
          if (RELU) v = fmaxf(v, 0.f);
          if (GATE) v *= gv;
          if (OSPLIT) {
            f16 h, l; fsplit(v, h, l);
            Ch[grow * ldc + col] = h;
            Cl[grow * ldc + col] = l;
          } else if (KS > 1) {
            atomicAdd(&Cf[grow * ldc + col], v);
          } else {
            Cf[grow * ldc + col] = v;
          }
        }
      }
    }
  }
}

// ---------------------------------------------------------------------------
// Split-fp16 MFMA flash attention. Wave = 16 queries, 32-key tiles.
// grid: (B*H, T/64)
// ---------------------------------------------------------------------------
__global__ __launch_bounds__(256)
void attn_mfma(const f16* __restrict__ Qh, const f16* __restrict__ Ql, int sq, int oq,
               const f16* __restrict__ Kh, const f16* __restrict__ Kl, int sk, int ok,
               const f16* __restrict__ Vh, const f16* __restrict__ Vl, int sv, int ov,
               f16* __restrict__ Oh, f16* __restrict__ Ol,
               const int* __restrict__ amask, int causal, int nK) {
  __shared__ f16 Ksh[32 * 64];
  __shared__ f16 Ksl[32 * 64];
  __shared__ f16 Vth[64 * 32];
  __shared__ f16 Vtl[64 * 32];
  __shared__ f16 Psh[4 * 16 * 32];
  __shared__ f16 Psl[4 * 16 * 32];

  int bh = blockIdx.x;
  int b = bh >> 3, hd = bh & 7;
  int t = threadIdx.x;
  int wv = t >> 6, lane = t & 63;
  int quad = lane >> 4, m16 = lane & 15;
  int qfrow = blockIdx.y * 64 + wv * 16 + m16;
  int qcbase = blockIdx.y * 64 + wv * 16 + quad * 4;

  size_t qoff = (size_t)(b * Tt + qfrow) * sq + oq + hd * 64;
  f16x8 qh0 = *reinterpret_cast<const f16x8*>(Qh + qoff + quad * 8);
  f16x8 qh1 = *reinterpret_cast<const f16x8*>(Qh + qoff + 32 + quad * 8);
  f16x8 ql0 = *reinterpret_cast<const f16x8*>(Ql + qoff + quad * 8);
  f16x8 ql1 = *reinterpret_cast<const f16x8*>(Ql + qoff + 32 + quad * 8);

  f32x4 Om[4], Oc[4];
#pragma unroll
  for (int c = 0; c < 4; c++) {
    Om[c] = (f32x4){0.f, 0.f, 0.f, 0.f};
    Oc[c] = (f32x4){0.f, 0.f, 0.f, 0.f};
  }
  float mr[4] = {-1e30f, -1e30f, -1e30f, -1e30f};
  float lrw[4] = {0.f, 0.f, 0.f, 0.f};

  int NT = causal ? (blockIdx.y * 2 + 2) : (nK >> 5);
  int myNT = causal ? (((blockIdx.y * 64 + wv * 16 + 15) >> 5) + 1) : NT;

  int rk = t >> 3, gs = t & 7, gsrc = gs ^ (rk & 7);
  int rv = t & 31, gv = t >> 5;

  for (int kt = 0; kt < NT; ++kt) {
    __syncthreads();
    {
      size_t krow = (size_t)(b * 1024 + kt * 32 + rk) * sk + ok + hd * 64 + gsrc * 8;
      *reinterpret_cast<f16x8*>(&Ksh[t * 8]) = *reinterpret_cast<const f16x8*>(Kh + krow);
      *reinterpret_cast<f16x8*>(&Ksl[t * 8]) = *reinterpret_cast<const f16x8*>(Kl + krow);
      size_t vrow = (size_t)(b * 1024 + kt * 32 + rv) * sv + ov + hd * 64 + gv * 8;
      f16x8 vh8 = *reinterpret_cast<const f16x8*>(Vh + vrow);
      f16x8 vl8 = *reinterpret_cast<const f16x8*>(Vl + vrow);
#pragma unroll
      for (int i = 0; i < 8; i++) {
        Vth[(gv * 8 + i) * 32 + rv] = vh8[i];
        Vtl[(gv * 8 + i) * 32 + rv] = vl8[i];
      }
    }
    __syncthreads();

    if (kt < myNT) {
      f32x4 S0m = (f32x4){0.f, 0.f, 0.f, 0.f}, S0c = S0m, S1m = S0m, S1c = S0m;
      {
        int key0 = m16, key1 = 16 + m16;
        int g0a = (quad) ^ (key0 & 7), g0b = (4 + quad) ^ (key0 & 7);
        int g1a = (quad) ^ (key1 & 7), g1b = (4 + quad) ^ (key1 & 7);
        f16x8 kh0a = *reinterpret_cast<const f16x8*>(&Ksh[key0 * 64 + g0a * 8]);
        f16x8 kh0b = *reinterpret_cast<const f16x8*>(&Ksh[key0 * 64 + g0b * 8]);
        f16x8 kl0a = *reinterpret_cast<const f16x8*>(&Ksl[key0 * 64 + g0a * 8]);
        f16x8 kl0b = *reinterpret_cast<const f16x8*>(&Ksl[key0 * 64 + g0b * 8]);
        S0m = __builtin_amdgcn_mfma_f32_16x16x32_f16(qh0, kh0a, S0m, 0, 0, 0);
        S0m = __builtin_amdgcn_mfma_f32_16x16x32_f16(qh1, kh0b, S0m, 0, 0, 0);
        S0c = __builtin_amdgcn_mfma_f32_16x16x32_f16(qh0, kl0a, S0c, 0, 0, 0);
        S0c = __builtin_amdgcn_mfma_f32_16x16x32_f16(qh1, kl0b, S0c, 0, 0, 0);
        S0c = __builtin_amdgcn_mfma_f32_16x16x32_f16(ql0, kh0a, S0c, 0, 0, 0);
        S0c = __builtin_amdgcn_mfma_f32_16x16x32_f16(ql1, kh0b, S0c, 0, 0, 0);
        f16x8 kh1a = *reinterpret_cast<const f16x8*>(&Ksh[key1 * 64 + g1a * 8]);
        f16x8 kh1b = *reinterpret_cast<const f16x8*>(&Ksh[key1 * 64 + g1b * 8]);
        f16x8 kl1a = *reinterpret_cast<const f16x8*>(&Ksl[key1 * 64 + g1a * 8]);
        f16x8 kl1b = *reinterpret_cast<const f16x8*>(&Ksl[key1 * 64 + g1b * 8]);
        S1m = __builtin_amdgcn_mfma_f32_16x16x32_f16(qh0, kh1a, S1m, 0, 0, 0);
        S1m = __builtin_amdgcn_mfma_f32_16x16x32_f16(qh1, kh1b, S1m, 0, 0, 0);
        S1c = __builtin_amdgcn_mfma_f32_16x16x32_f16(qh0, kl1a, S1c, 0, 0, 0);
        S1c = __builtin_amdgcn_mfma_f32_16x16x32_f16(qh1, kl1b, S1c, 0, 0, 0);
        S1c = __builtin_amdgcn_mfma_f32_16x16x32_f16(ql0, kh1a, S1c, 0, 0, 0);
        S1c = __builtin_amdgcn_mfma_f32_16x16x32_f16(ql1, kh1b, S1c, 0, 0, 0);
      }
      float S0[4], S1[4];
      int key0 = kt * 32 + m16, key1 = kt * 32 + 16 + m16;
      int am0 = amask ? amask[b * nK + key0] : 1;
      int am1 = amask ? amask[b * nK + key1] : 1;
#pragma unroll
      for (int reg = 0; reg < 4; reg++) {
        int qr = qcbase + reg;
        bool ok0 = am0 && (!causal || key0 <= qr);
        bool ok1 = am1 && (!causal || key1 <= qr);
        S0[reg] = ok0 ? (S0m[reg] + S0c[reg] * ILOSC) * 0.125f : -1e9f;
        S1[reg] = ok1 ? (S1m[reg] + S1c[reg] * ILOSC) * 0.125f : -1e9f;
      }
      float mt[4], al4[4], rs[4];
#pragma unroll
      for (int reg = 0; reg < 4; reg++) mt[reg] = fmaxf(S0[reg], S1[reg]);
#pragma unroll
      for (int off = 1; off < 16; off <<= 1)
#pragma unroll
        for (int reg = 0; reg < 4; reg++) mt[reg] = fmaxf(mt[reg], __shfl_xor(mt[reg], off, 64));
#pragma unroll
      for (int reg = 0; reg < 4; reg++) {
        float mn = fmaxf(mr[reg], mt[reg]);
        al4[reg] = expf(mr[reg] - mn);
        mr[reg] = mn;
        S0[reg] = expf(S0[reg] - mn);
        S1[reg] = expf(S1[reg] - mn);
        rs[reg] = S0[reg] + S1[reg];
      }
#pragma unroll
      for (int off = 1; off < 16; off <<= 1)
#pragma unroll
        for (int reg = 0; reg < 4; reg++) rs[reg] += __shfl_xor(rs[reg], off, 64);
#pragma unroll
      for (int reg = 0; reg < 4; reg++) {
        lrw[reg] = lrw[reg] * al4[reg] + rs[reg];
#pragma unroll
        for (int c = 0; c < 4; c++) { Om[c][reg] *= al4[reg]; Oc[c][reg] *= al4[reg]; }
        int prow = wv * 16 + quad * 4 + reg;
        f16 ph, pl;
        fsplit(S0[reg], ph, pl);
        Psh[prow * 32 + m16] = ph; Psl[prow * 32 + m16] = pl;
        fsplit(S1[reg], ph, pl);
        Psh[prow * 32 + 16 + m16] = ph; Psl[prow * 32 + 16 + m16] = pl;
      }
      __builtin_amdgcn_sched_barrier(0);
      f16x8 pah = *reinterpret_cast<const f16x8*>(&Psh[(wv * 16 + m16) * 32 + quad * 8]);
      f16x8 pal = *reinterpret_cast<const f16x8*>(&Psl[(wv * 16 + m16) * 32 + quad * 8]);
#pragma unroll
      for (int c = 0; c < 4; c++) {
        f16x8 vbh = *reinterpret_cast<const f16x8*>(&Vth[(c * 16 + m16) * 32 + quad * 8]);
        f16x8 vbl = *reinterpret_cast<const f16x8*>(&Vtl[(c * 16 + m16) * 32 + quad * 8]);
        Om[c] = __builtin_amdgcn_mfma_f32_16x16x32_f16(pah, vbh, Om[c], 0, 0, 0);
        Oc[c] = __builtin_amdgcn_mfma_f32_16x16x32_f16(pah, vbl, Oc[c], 0, 0, 0);
        Oc[c] = __builtin_amdgcn_mfma_f32_16x16x32_f16(pal, vbh, Oc[c], 0, 0, 0);
      }
    }
  }
#pragma unroll
  for (int reg = 0; reg < 4; reg++) {
    int qr = qcbase + reg;
    float inv = 1.f / lrw[reg];
#pragma unroll
    for (int c = 0; c < 4; c++) {
      float o = (Om[c][reg] + Oc[c][reg] * ILOSC) * inv;
      f16 hh, ll; fsplit(o, hh, ll);
      size_t oo = (size_t)(b * Tt + qr) * Dd + hd * 64 + c * 16 + m16;
      Oh[oo] = hh;
      Ol[oo] = ll;
    }
  }
}

// ---------------------------------------------------------------------------
__global__ __launch_bounds__(256)
void add_ln_kernel(float* __restrict__ Y, f16* __restrict__ Yh, f16* __restrict__ Yl,
                   const float* __restrict__ Aadd,
                   const float* __restrict__ g, const float* __restrict__ bb) {
  int tid = threadIdx.x;
  size_t base = (size_t)blockIdx.x * Dd;
  __shared__ float red[256];
  __shared__ float mu_s, rs_s;
  float x0 = Y[base + tid] + Aadd[base + tid];
  float x1 = Y[base + 256 + tid] + Aadd[base + 256 + tid];
  red[tid] = x0 + x1; __syncthreads();
  for (int s2 = 128; s2 > 0; s2 >>= 1) { if (tid < s2) red[tid] += red[tid + s2]; __syncthreads(); }
  if (tid == 0) mu_s = red[0] / (float)Dd;
  __syncthreads();
  float mu = mu_s;
  float d0 = x0 - mu, d1 = x1 - mu;
  red[tid] = d0 * d0 + d1 * d1; __syncthreads();
  for (int s2 = 128; s2 > 0; s2 >>= 1) { if (tid < s2) red[tid] += red[tid + s2]; __syncthreads(); }
  if (tid == 0) rs_s = rsqrtf(red[0] / (float)Dd + EPSF);
  __syncthreads();
  float rs = rs_s;
  float o0 = d0 * rs * g[tid] + bb[tid];
  float o1 = d1 * rs * g[256 + tid] + bb[256 + tid];
  f16 h, l;
  Y[base + tid] = o0; fsplit(o0, h, l); Yh[base + tid] = h; Yl[base + tid] = l;
  Y[base + 256 + tid] = o1; fsplit(o1, h, l); Yh[base + 256 + tid] = h; Yl[base + 256 + tid] = l;
}

__global__ __launch_bounds__(256)
void combine_ln_kernel(float* __restrict__ Y, f16* __restrict__ Yh, f16* __restrict__ Yl,
                       const float* __restrict__ pout, const int* __restrict__ slot,
                       const float* __restrict__ g, const float* __restrict__ bb) {
  int tid = threadIdx.x;
  int m = blockIdx.x;
  size_t base = (size_t)m * Dd;
  int s0 = slot[m * 2 + 0], s1 = slot[m * 2 + 1];
  __shared__ float red[256];
  __shared__ float mu_s, rs_s;
  float x0 = Y[base + tid] + pout[(size_t)s0 * Dd + tid] + pout[(size_t)s1 * Dd + tid];
  float x1 = Y[base + 256 + tid] + pout[(size_t)s0 * Dd + 256 + tid] + pout[(size_t)s1 * Dd + 256 + tid];
  red[tid] = x0 + x1; __syncthreads();
  for (int s2 = 128; s2 > 0; s2 >>= 1) { if (tid < s2) red[tid] += red[tid + s2]; __syncthreads(); }
  if (tid == 0) mu_s = red[0] / (float)Dd;
  __syncthreads();
  float mu = mu_s;
  float d0 = x0 - mu, d1 = x1 - mu;
  red[tid] = d0 * d0 + d1 * d1; __syncthreads();
  for (int s2 = 128; s2 > 0; s2 >>= 1) { if (tid < s2) red[tid] += red[tid + s2]; __syncthreads(); }
  if (tid == 0) rs_s = rsqrtf(red[0] / (float)Dd + EPSF);
  __syncthreads();
  float rs = rs_s;
  float o0 = d0 * rs * g[tid] + bb[tid];
  float o1 = d1 * rs * g[256 + tid] + bb[256 + tid];
  f16 h, l;
  Y[base + tid] = o0; fsplit(o0, h, l); Yh[base + tid] = h; Yl[base + tid] = l;
  Y[base + 256 + tid] = o1; fsplit(o1, h, l); Yh[base + 256 + tid] = h; Yl[base + 256 + tid] = l;
}

// ---------------------------------------------------------------------------
// Router v2: zero contended atomics.
// ---------------------------------------------------------------------------
__global__ __launch_bounds__(256)
void router_kernel(const float* __restrict__ Y, const float* __restrict__ rw,
                   const float* __restrict__ rb, float* __restrict__ gates,
                   int* __restrict__ topi, int* __restrict__ part_cnt,
                   float* __restrict__ part_sumP) {
  int wv = threadIdx.x >> 6, lane = threadIdx.x & 63;
  __shared__ float wsum[4][Ee];
  __shared__ int wcnt[4][Ee];
  float w[8][Ee];
#pragma unroll
  for (int dd = 0; dd < 8; dd++) {
    const float4* rp = reinterpret_cast<const float4*>(&rw[(size_t)(dd * 64 + lane) * Ee]);
    float4 a = rp[0], b4 = rp[1];
    w[dd][0] = a.x; w[dd][1] = a.y; w[dd][2] = a.z; w[dd][3] = a.w;
    w[dd][4] = b4.x; w[dd][5] = b4.y; w[dd][6] = b4.z; w[dd][7] = b4.w;
  }
  float rbv[Ee];
#pragma unroll
  for (int e = 0; e < Ee; e++) rbv[e] = rb[e];

  float psum[Ee]; int pcnt[Ee];
#pragma unroll
  for (int e = 0; e < Ee; e++) { psum[e] = 0.f; pcnt[e] = 0; }

  int m0 = blockIdx.x * 32 + wv * 8;
  for (int j = 0; j < 8; j++) {
    int m = m0 + j;
    const float* yr = Y + (size_t)m * Dd;
    float yv[8];
#pragma unroll
    for (int dd = 0; dd < 8; dd++) yv[dd] = yr[dd * 64 + lane];
    float acc[Ee];
#pragma unroll
    for (int e = 0; e < Ee; e++) acc[e] = 0.f;
#pragma unroll
    for (int dd = 0; dd < 8; dd++)
#pragma unroll
      for (int e = 0; e < Ee; e++) acc[e] += yv[dd] * w[dd][e];
#pragma unroll
    for (int off = 32; off; off >>= 1)
#pragma unroll
      for (int e = 0; e < Ee; e++) acc[e] += __shfl_xor(acc[e], off, 64);
    if (lane == 0) {
      float pv[Ee];
      float mx = -1e30f;
#pragma unroll
      for (int e = 0; e < Ee; e++) { pv[e] = acc[e] + rbv[e]; mx = fmaxf(mx, pv[e]); }
      float ssum = 0.f;
#pragma unroll
      for (int e = 0; e < Ee; e++) { pv[e] = expf(pv[e] - mx); ssum += pv[e]; }
      float invs = 1.f / ssum;
#pragma unroll
      for (int e = 0; e < Ee; e++) { pv[e] *= invs; psum[e] += pv[e]; }
      int i1 = 0;
#pragma unroll
      for (int e = 1; e < Ee; e++) if (pv[e] > pv[i1]) i1 = e;
      int i2 = (i1 == 0) ? 1 : 0;
#pragma unroll
      for (int e = 0; e < Ee; e++) if (e != i1 && pv[e] > pv[i2]) i2 = e;
      float gs = pv[i1] + pv[i2];
      gates[m * 2 + 0] = pv[i1] / gs;
      gates[m * 2 + 1] = pv[i2] / gs;
      topi[m * 2 + 0] = i1;
      topi[m * 2 + 1] = i2;
#pragma unroll
      for (int e = 0; e < Ee; e++) pcnt[e] += (e == i1) + (e == i2);
    }
  }
  if (lane == 0) {
#pragma unroll
    for (int e = 0; e < Ee; e++) { wsum[wv][e] = psum[e]; wcnt[wv][e] = pcnt[e]; }
  }
  __syncthreads();
  if (threadIdx.x < Ee) {
    int e = threadIdx.x;
    float s = wsum[0][e] + wsum[1][e] + wsum[2][e] + wsum[3][e];
    int c = wcnt[0][e] + wcnt[1][e] + wcnt[2][e] + wcnt[3][e];
    part_sumP[blockIdx.x * Ee + e] = s;
    part_cnt[blockIdx.x * Ee + e] = c;
  }
}

__global__ void prefix_lb_kernel(const int* __restrict__ part_cnt,
                                 const float* __restrict__ part_sumP,
                                 int* __restrict__ cnt, int* __restrict__ offs,
                                 int* __restrict__ fill, float* __restrict__ lb_acc) {
  __shared__ int sc[Ee];
  __shared__ float ss[Ee];
  int t = threadIdx.x;
  if (t < Ee) {
    int c = 0; float s = 0.f;
    for (int b2 = 0; b2 < RBLK; b2++) { c += part_cnt[b2 * Ee + t]; s += part_sumP[b2 * Ee + t]; }
    sc[t] = c; ss[t] = s;
    cnt[t] = c; fill[t] = 0;
  }
  __syncthreads();
  if (t == 0) {
    int run = 0;
    float lb = 0.f;
    for (int e = 0; e < Ee; e++) {
      offs[e] = run; run += sc[e];
      lb += ((float)sc[e] * IMm) * (ss[e] * IMm);
    }
    *lb_acc += (float)Ee * lb;
  }
}

__global__ __launch_bounds__(256)
void scatter_kernel(const int* __restrict__ topi, const float* __restrict__ gates,
                    const int* __restrict__ offs, int* __restrict__ fill,
                    int* __restrict__ pair_tok, float* __restrict__ pair_gate,
                    int* __restrict__ slot) {
  __shared__ int lcnt[Ee];
  __shared__ int lbase[Ee];
  int t = threadIdx.x;
  int m = blockIdx.x * 256 + t;
  if (t < Ee) lcnt[t] = 0;
  __syncthreads();
  int e0 = topi[m * 2 + 0], e1 = topi[m * 2 + 1];
  float g0 = gates[m * 2 + 0], g1 = gates[m * 2 + 1];
  int p0 = atomicAdd(&lcnt[e0], 1);
  int p1 = atomicAdd(&lcnt[e1], 1);
  __syncthreads();
  if (t < Ee) lbase[t] = atomicAdd(&fill[t], lcnt[t]);
  __syncthreads();
  int i0 = offs[e0] + lbase[e0] + p0;
  int i1 = offs[e1] + lbase[e1] + p1;
  pair_tok[i0] = m; pair_gate[i0] = g0; slot[m * 2 + 0] = i0;
  pair_tok[i1] = m; pair_gate[i1] = g1; slot[m * 2 + 1] = i1;
}

__global__ void init_lb_kernel(float* lb_acc) {
  if (threadIdx.x == 0) *lb_acc = 0.f;
}

__global__ void finalize_kernel(const float* __restrict__ Y,
                                const float* __restrict__ lb_acc,
                                float* __restrict__ out) {
  size_t i = (size_t)blockIdx.x * 256 + threadIdx.x;
  const size_t n = (size_t)Mm * Dd;
  if (i < n) out[i] = Y[i];
  if (i == 0) out[n] = *lb_acc;
}

// ---------------------------------------------------------------------------
extern "C" void kernel_launch(void* const* d_in, const int* in_sizes, int n_in,
                              void* d_out, int out_size, void* d_ws, size_t ws_size,
                              hipStream_t stream) {
  const int*   ids   = (const int*)d_in[0];
  const float* enc   = (const float*)d_in[1];
  const int*   amask = (const int*)d_in[2];
  const float* emb   = (const float*)d_in[3];
  const float* pos   = (const float*)d_in[4];
  const float* sa_w  = (const float*)d_in[5];
  const float* sa_b  = (const float*)d_in[6];
  const float* ca_w  = (const float*)d_in[7];
  const float* ca_b  = (const float*)d_in[8];
  const float* ln_g  = (const float*)d_in[9];
  const float* ln_b  = (const float*)d_in[10];
  const float* rw    = (const float*)d_in[11];
  const float* rb    = (const float*)d_in[12];
  const float* ew1   = (const float*)d_in[13];
  const float* eb1   = (const float*)d_in[14];
  const float* ew2   = (const float*)d_in[15];
  const float* eb2   = (const float*)d_in[16];
  float* out = (float*)d_out;

  char* p = (char*)d_ws;
  auto alloc = [&](size_t bytes) { void* r = p; p += (bytes + 255) & ~(size_t)255; return r; };
  float* y    = (float*)alloc((size_t)Mm * Dd * 4);
  float* proj = (float*)alloc((size_t)Mm * Dd * 4);
  float* pout = (float*)alloc((size_t)NPp * Dd * 4);
  f16* yh   = (f16*)alloc((size_t)Mm * Dd * 2);
  f16* yl   = (f16*)alloc((size_t)Mm * Dd * 2);
  f16* ench = (f16*)alloc((size_t)Mm * Dd * 2);
  f16* encl = (f16*)alloc((size_t)Mm * Dd * 2);
  f16* qkvh = (f16*)alloc((size_t)Mm * 1536 * 2);
  f16* qkvl = (f16*)alloc((size_t)Mm * 1536 * 2);
  f16* qch  = (f16*)alloc((size_t)Mm * Dd * 2);
  f16* qcl  = (f16*)alloc((size_t)Mm * Dd * 2);
  f16* atth = (f16*)alloc((size_t)Mm * Dd * 2);
  f16* attl = (f16*)alloc((size_t)Mm * Dd * 2);
  f16* ckvh = (f16*)alloc((size_t)Mm * 1024 * 2);
  f16* ckvl = (f16*)alloc((size_t)Mm * 1024 * 2);
  f16* moeh = (f16*)alloc((size_t)NPp * FFf * 2);
  f16* moel = (f16*)alloc((size_t)NPp * FFf * 2);
  f16* saTh = (f16*)alloc((size_t)Ll * 4 * DD_ * 2);
  f16* saTl = (f16*)alloc((size_t)Ll * 4 * DD_ * 2);
  f16* caTh = (f16*)alloc((size_t)Ll * 4 * DD_ * 2);
  f16* caTl = (f16*)alloc((size_t)Ll * 4 * DD_ * 2);
  f16* w1Th = (f16*)alloc((size_t)Ee * Dd * FFf * 2);
  f16* w1Tl = (f16*)alloc((size_t)Ee * Dd * FFf * 2);
  f16* w2Th = (f16*)alloc((size_t)Ee * Dd * FFf * 2);
  f16* w2Tl = (f16*)alloc((size_t)Ee * Dd * FFf * 2);
  float* gates     = (float*)alloc((size_t)Mm * 2 * 4);
  float* pair_gate = (float*)alloc((size_t)NPp * 4);
  float* part_sumP = (float*)alloc((size_t)RBLK * Ee * 4);
  float* lb_acc    = (float*)alloc(4);
  int* topi     = (int*)alloc((size_t)Mm * 2 * 4);
  int* pair_tok = (int*)alloc((size_t)NPp * 4);
  int* slot     = (int*)alloc((size_t)Mm * 2 * 4);
  int* part_cnt = (int*)alloc((size_t)RBLK * Ee * 4);
  int* cnt      = (int*)alloc(Ee * 4);
  int* offs     = (int*)alloc(Ee * 4);
  int* fill     = (int*)alloc(Ee * 4);

  init_lb_kernel<<<1, 64, 0, stream>>>(lb_acc);
  embed_kernel<<<Mm, 256, 0, stream>>>(ids, emb, pos, y, yh, yl);
  cvt_split_kernel<<<(Mm * Dd) / 1024, 256, 0, stream>>>(enc, ench, encl);
  transpose_split<<<dim3(16, 16, 16), 256, 0, stream>>>(sa_w, saTh, saTl, Dd, Dd);
  transpose_split<<<dim3(16, 16, 16), 256, 0, stream>>>(ca_w, caTh, caTl, Dd, Dd);

  dim3 gAttn(Bb * Hh, Tt / 64);

  for (int i = 0; i < Ll; i++) {
    transpose_split<<<dim3(64, 16, 8), 256, 0, stream>>>(ew1 + (size_t)i * Ee * Dd * FFf, w1Th, w1Tl, Dd, FFf);
    transpose_split<<<dim3(16, 64, 8), 256, 0, stream>>>(ew2 + (size_t)i * Ee * FFf * Dd, w2Th, w2Tl, FFf, Dd);

    const f16* saThl = saTh + (size_t)i * 4 * DD_;
    const f16* saTll = saTl + (size_t)i * 4 * DD_;
    const f16* caThl = caTh + (size_t)i * 4 * DD_;
    const f16* caTll = caTl + (size_t)i * 4 * DD_;
    const float* sabl = sa_b + (size_t)i * 4 * Dd;
    const float* cabl = ca_b + (size_t)i * 4 * Dd;

    // cross K,V (fused N=1024)
    mm128<false, true, false, false, 1><<<dim3(8, 16, 1), 256, 0, stream>>>(
        ench, encl, Dd, caThl + DD_, caTll + DD_, cabl + Dd,
        nullptr, ckvh, ckvl, 1024, Mm, 1024, Dd, nullptr, nullptr, nullptr, nullptr);
    // self QKV (fused N=1536)
    mm128<false, true, false, false, 1><<<dim3(12, 16, 1), 256, 0, stream>>>(
        yh, yl, Dd, saThl, saTll, sabl,
        nullptr, qkvh, qkvl, 1536, Mm, 1536, Dd, nullptr, nullptr, nullptr, nullptr);
    // self attention
    attn_mfma<<<gAttn, 256, 0, stream>>>(qkvh, qkvl, 1536, 0, qkvh, qkvl, 1536, 512,
                                         qkvh, qkvl, 1536, 1024, atth, attl, amask, 1, Tt);
    // self out-proj
    mm128<false, false, false, false, 1><<<dim3(4, 16, 1), 256, 0, stream>>>(
        atth, attl, Dd, saThl + 3 * DD_, saTll + 3 * DD_, sabl + 3 * Dd,
        proj, nullptr, nullptr, Dd, Mm, Dd, Dd, nullptr, nullptr, nullptr, nullptr);
    add_ln_kernel<<<Mm, 256, 0, stream>>>(y, yh, yl, proj,
                                          ln_g + (size_t)(i * 3 + 0) * Dd, ln_b + (size_t)(i * 3 + 0) * Dd);
    // cross Q
    mm128<false, true, false, false, 1><<<dim3(4, 16, 1), 256, 0, stream>>>(
        yh, yl, Dd, caThl, caTll, cabl,
        nullptr, qch, qcl, Dd, Mm, Dd, Dd, nullptr, nullptr, nullptr, nullptr);
    // cross attention
    attn_mfma<<<gAttn, 256, 0, stream>>>(qch, qcl, Dd, 0, ckvh, ckvl, 1024, 0,
                                         ckvh, ckvl, 1024, 512, atth, attl, nullptr, 0, Ss);
    // cross out-proj
    mm128<false, false, false, false, 1><<<dim3(4, 16, 1), 256, 0, stream>>>(
        atth, attl, Dd, caThl + 3 * DD_, caTll + 3 * DD_, cabl + 3 * Dd,
        proj, nullptr, nullptr, Dd, Mm, Dd, Dd, nullptr, nullptr, nullptr, nullptr);
    add_ln_kernel<<<Mm, 256, 0, stream>>>(y, yh, yl, proj,
                                          ln_g + (size_t)(i * 3 + 1) * Dd, ln_b + (size_t)(i * 3 + 1) * Dd);
    // MoE (atomic-free router)
    router_kernel<<<RBLK, 256, 0, stream>>>(y, rw + (size_t)i * Dd * Ee, rb + (size_t)i * Ee,
                                            gates, topi, part_cnt, part_sumP);
    prefix_lb_kernel<<<1, 64, 0, stream>>>(part_cnt, part_sumP, cnt, offs, lb_acc ? fill : fill, lb_acc);
    scatter_kernel<<<Mm / 256, 256, 0, stream>>>(topi, gates, offs, fill, pair_tok, pair_gate, slot);
    zero_kernel<<<((size_t)NPp * Dd) / 1024, 256, 0, stream>>>(pout);
    mm128<true, true, true, false, 1><<<dim3(16, 32, 8), 256, 0, stream>>>(
        yh, yl, Dd, w1Th, w1Tl, eb1 + (size_t)i * Ee * FFf,
        nullptr, moeh, moel, FFf, NPp, FFf, Dd, pair_tok, nullptr, offs, cnt);
    // w2: split-K x4, atomicAdd partials into pre-zeroed pout
    mm128<false, false, false, true, 4><<<dim3(4, 32, Ee * 4), 256, 0, stream>>>(
        moeh, moel, FFf, w2Th, w2Tl, eb2 + (size_t)i * Ee * Dd,
        pout, nullptr, nullptr, Dd, NPp, Dd, FFf, nullptr, pair_gate, offs, cnt);
    combine_ln_kernel<<<Mm, 256, 0, stream>>>(y, yh, yl, pout, slot,
                                              ln_g + (size_t)(i * 3 + 2) * Dd, ln_b + (size_t)(i * 3 + 2) * Dd);
  }

  finalize_kernel<<<(int)(((size_t)Mm * Dd + 256) / 256) + 1, 256, 0, stream>>>(y, lb_acc, out);
}

// Round 3
// 2437.490 us; speedup vs baseline: 1.1786x; 1.1786x over previous
//
#include <hip/hip_runtime.h>
#include <math.h>

#define Bb 2
#define Tt 1024
#define Ss 1024
#define Dd 512
#define Hh 8
#define Ll 4
#define Ee 8
#define FFf 2048
#define Mm 2048
#define NPp 4096
#define EPSF 1e-5f
#define DD_ (Dd*Dd)
#define LOSC 1024.0f
#define ILOSC (1.0f/1024.0f)
#define RBLK 64   // router blocks (Mm/32)
#define IMm (1.0f/(float)Mm)

typedef _Float16 f16;
typedef __attribute__((ext_vector_type(8))) _Float16 f16x8;
typedef __attribute__((ext_vector_type(4))) _Float16 f16x4;
typedef __attribute__((ext_vector_type(4))) float f32x4;

// split: x = hi + lo/1024 (lo pre-scaled by 1024 so it stays fp16-normal)
__device__ __forceinline__ void fsplit(float x, f16& h, f16& l) {
  h = (f16)x;
  l = (f16)((x - (float)h) * LOSC);
}

__device__ __forceinline__ void load16(const void* g, void* l) {
  __builtin_amdgcn_global_load_lds(
      (const __attribute__((address_space(1))) void*)g,
      (__attribute__((address_space(3))) void*)l, 16, 0, 0);
}

// ---------------------------------------------------------------------------
__global__ void embed_kernel(const int* __restrict__ ids,
                             const float* __restrict__ emb,
                             const float* __restrict__ pos,
                             float* __restrict__ Y,
                             f16* __restrict__ Yh, f16* __restrict__ Yl) {
  int m = blockIdx.x;
  int t = m % Tt;
  int id = ids[m];
  for (int d = threadIdx.x; d < Dd; d += 256) {
    float v = emb[(size_t)id * Dd + d] + pos[(size_t)t * Dd + d];
    Y[(size_t)m * Dd + d] = v;
    f16 h, l; fsplit(v, h, l);
    Yh[(size_t)m * Dd + d] = h;
    Yl[(size_t)m * Dd + d] = l;
  }
}

__global__ void cvt_split_kernel(const float* __restrict__ src,
                                 f16* __restrict__ dh, f16* __restrict__ dl) {
  size_t i = ((size_t)blockIdx.x * 256 + threadIdx.x) * 4;
  float4 v = *reinterpret_cast<const float4*>(&src[i]);
  float a[4] = {v.x, v.y, v.z, v.w};
#pragma unroll
  for (int j = 0; j < 4; j++) { f16 h, l; fsplit(a[j], h, l); dh[i + j] = h; dl[i + j] = l; }
}

// ---------------------------------------------------------------------------
// Batched transpose+split: src[z]=[Kd,Nd] fp32 -> dstH/dstL[z]=[Nd,Kd] fp16
// ---------------------------------------------------------------------------
__global__ __launch_bounds__(256)
void transpose_split(const float* __restrict__ src,
                     f16* __restrict__ dstH, f16* __restrict__ dstL,
                     int Kd, int Nd) {
  __shared__ float Tl[32][33];
  size_t zo = (size_t)blockIdx.z * Kd * Nd;
  int k0 = blockIdx.y * 32, n0 = blockIdx.x * 32;
  int t = threadIdx.x;
  int r = t >> 3, c = t & 7;
  float4 v = *reinterpret_cast<const float4*>(&src[zo + (size_t)(k0 + r) * Nd + n0 + c * 4]);
  Tl[r][c * 4 + 0] = v.x; Tl[r][c * 4 + 1] = v.y;
  Tl[r][c * 4 + 2] = v.z; Tl[r][c * 4 + 3] = v.w;
  __syncthreads();
  int nl = t >> 3, kq = t & 7;
  f16x4 hv, lv;
#pragma unroll
  for (int i = 0; i < 4; i++) {
    f16 h, l; fsplit(Tl[kq * 4 + i][nl], h, l);
    hv[i] = h; lv[i] = l;
  }
  size_t o = zo + (size_t)(n0 + nl) * Kd + k0 + kq * 4;
  *reinterpret_cast<f16x4*>(&dstH[o]) = hv;
  *reinterpret_cast<f16x4*>(&dstL[o]) = lv;
}

// ---------------------------------------------------------------------------
// 128x128 split-fp16 MFMA GEMM (3-product), double-buffered LDS (2-phase).
// A hi/lo [*,K], B hi/lo [N,K].
// KS>1: split-K over blockIdx.z (z = expert*KS + kslice); slice ks writes
// plain stores into Cf + ks*Mtot*ldc (bias in slice 0 only; no atomics).
// LDS slot-XOR swizzle: linear global_load_lds dest, pre-swizzled global
// source slot (cc ^ ((rr>>1)&3)), swizzled ds_read slot (quad ^ ((m16>>1)&3)).
// ---------------------------------------------------------------------------
template <bool GATHER, bool OSPLIT, bool RELU, bool GATE, int KS>
__global__ __launch_bounds__(256)
void mm128(const f16* __restrict__ Ah_, const f16* __restrict__ Al_, int lda,
           const f16* __restrict__ Bh_, const f16* __restrict__ Bl_,
           const float* __restrict__ bias,
           float* __restrict__ Cf, f16* __restrict__ Ch, f16* __restrict__ Cl, int ldc,
           int Mtot, int N, int K,
           const int* __restrict__ tok, const float* __restrict__ gate,
           const int* __restrict__ offs, const int* __restrict__ cnt) {
  __shared__ f16 Ash[2][128 * 32];
  __shared__ f16 Asl[2][128 * 32];
  __shared__ f16 Bsh[2][128 * 32];
  __shared__ f16 Bsl[2][128 * 32];
  int zz = blockIdx.z;
  int e  = (KS > 1) ? (zz / KS) : zz;
  int ks = (KS > 1) ? (zz % KS) : 0;
  int base = 0, ne = Mtot;
  if (offs) { base = offs[e]; ne = cnt[e]; }
  int m0 = blockIdx.y * 128;
  if (m0 >= ne) return;
  int rem = ne - m0;
  Bh_ += (size_t)e * N * K;
  Bl_ += (size_t)e * N * K;
  bias += (size_t)e * N;
  if (KS > 1) Cf += (size_t)ks * (size_t)Mtot * (size_t)ldc;

  int t = threadIdx.x;
  int rr = t >> 2, cc = t & 3;
  int csw = cc ^ ((rr >> 1) & 3);   // pre-swizzled source slot
  int gr0 = base + m0 + rr;      if (gr0 > Mtot - 1) gr0 = Mtot - 1;
  int gr1 = base + m0 + rr + 64; if (gr1 > Mtot - 1) gr1 = Mtot - 1;
  int arow0 = GATHER ? tok[gr0] : gr0;
  int arow1 = GATHER ? tok[gr1] : gr1;
  size_t aoff0 = (size_t)arow0 * lda + csw * 8;
  size_t aoff1 = (size_t)arow1 * lda + csw * 8;
  size_t boff0 = (size_t)(blockIdx.x * 128 + rr) * K + csw * 8;
  size_t boff1 = (size_t)(blockIdx.x * 128 + rr + 64) * K + csw * 8;

  int lane = t & 63, wv = t >> 6;
  int quad = lane >> 4, m16 = lane & 15;
  int sw = quad ^ ((m16 >> 1) & 3);  // swizzled read slot
  int wm = (wv >> 1) * 64, wn = (wv & 1) * 64;

  f32x4 accm[4][4], accc[4][4];
#pragma unroll
  for (int i = 0; i < 4; i++)
#pragma unroll
    for (int j = 0; j < 4; j++) {
      accm[i][j] = (f32x4){0.f, 0.f, 0.f, 0.f};
      accc[i][j] = (f32x4){0.f, 0.f, 0.f, 0.f};
    }

  int kper = K / KS;
  int kbeg = ks * kper;
  int nt = kper >> 5;

  auto STAGE = [&](int bf, int kc) {
    load16(Ah_ + aoff0 + kc, &Ash[bf][t * 8]);
    load16(Ah_ + aoff1 + kc, &Ash[bf][2048 + t * 8]);
    load16(Al_ + aoff0 + kc, &Asl[bf][t * 8]);
    load16(Al_ + aoff1 + kc, &Asl[bf][2048 + t * 8]);
    load16(Bh_ + boff0 + kc, &Bsh[bf][t * 8]);
    load16(Bh_ + boff1 + kc, &Bsh[bf][2048 + t * 8]);
    load16(Bl_ + boff0 + kc, &Bsl[bf][t * 8]);
    load16(Bl_ + boff1 + kc, &Bsl[bf][2048 + t * 8]);
  };

  // prologue: stage tile 0, drain, barrier
  STAGE(0, kbeg);
  asm volatile("s_waitcnt vmcnt(0)" ::: "memory");
  __builtin_amdgcn_s_barrier();

  for (int tt = 0; tt < nt; ++tt) {
    int bf = tt & 1;
    if (tt + 1 < nt) STAGE(bf ^ 1, kbeg + (tt + 1) * 32);  // prefetch next
    f16x8 ah[4], al[4];
#pragma unroll
    for (int i = 0; i < 4; i++) {
      ah[i] = *reinterpret_cast<const f16x8*>(&Ash[bf][(wm + i * 16 + m16) * 32 + sw * 8]);
      al[i] = *reinterpret_cast<const f16x8*>(&Asl[bf][(wm + i * 16 + m16) * 32 + sw * 8]);
    }
#pragma unroll
    for (int j = 0; j < 4; j++) {
      f16x8 bh = *reinterpret_cast<const f16x8*>(&Bsh[bf][(wn + j * 16 + m16) * 32 + sw * 8]);
      f16x8 bl = *reinterpret_cast<const f16x8*>(&Bsl[bf][(wn + j * 16 + m16) * 32 + sw * 8]);
#pragma unroll
      for (int i = 0; i < 4; i++) {
        accm[i][j] = __builtin_amdgcn_mfma_f32_16x16x32_f16(ah[i], bh, accm[i][j], 0, 0, 0);
        accc[i][j] = __builtin_amdgcn_mfma_f32_16x16x32_f16(ah[i], bl, accc[i][j], 0, 0, 0);
        accc[i][j] = __builtin_amdgcn_mfma_f32_16x16x32_f16(al[i], bh, accc[i][j], 0, 0, 0);
      }
    }
    // wait for prefetch (hidden under the MFMAs above), then release buffers
    asm volatile("s_waitcnt vmcnt(0)" ::: "memory");
    __builtin_amdgcn_s_barrier();
  }

#pragma unroll
  for (int i = 0; i < 4; i++) {
#pragma unroll
    for (int reg = 0; reg < 4; reg++) {
      int lr = wm + i * 16 + quad * 4 + reg;
      if (lr < rem) {
        size_t grow = (size_t)(base + m0 + lr);
        float gv = 1.f;
        if (GATE) gv = gate[grow];
#pragma unroll
        for (int j = 0; j < 4; j++) {
          int col = blockIdx.x * 128 + wn + j * 16 + m16;
          float bv = (KS == 1 || ks == 0) ? bias[col] : 0.f;
          float v = accm[i][j][reg] + accc[i][j][reg] * ILOSC + bv;
          if (RELU) v = fmaxf(v, 0.f);
          if (GATE) v *= gv;
          if (OSPLIT) {
            f16 h, l; fsplit(v, h, l);
            Ch[grow * ldc + col] = h;
            Cl[grow * ldc + col] = l;
          } else {
            Cf[grow * ldc + col] = v;
          }
        }
      }
    }
  }
}

// ---------------------------------------------------------------------------
// Split-fp16 MFMA flash attention. Wave = 16 queries, 32-key tiles.
// grid: (B*H, T/64)
// ---------------------------------------------------------------------------
__global__ __launch_bounds__(256)
void attn_mfma(const f16* __restrict__ Qh, const f16* __restrict__ Ql, int sq, int oq,
               const f16* __restrict__ Kh, const f16* __restrict__ Kl, int sk, int ok,
               const f16* __restrict__ Vh, const f16* __restrict__ Vl, int sv, int ov,
               f16* __restrict__ Oh, f16* __restrict__ Ol,
               const int* __restrict__ amask, int causal, int nK) {
  __shared__ f16 Ksh[32 * 64];
  __shared__ f16 Ksl[32 * 64];
  __shared__ f16 Vth[64 * 32];
  __shared__ f16 Vtl[64 * 32];
  __shared__ f16 Psh[4 * 16 * 32];
  __shared__ f16 Psl[4 * 16 * 32];

  int bh = blockIdx.x;
  int b = bh >> 3, hd = bh & 7;
  int t = threadIdx.x;
  int wv = t >> 6, lane = t & 63;
  int quad = lane >> 4, m16 = lane & 15;
  int qfrow = blockIdx.y * 64 + wv * 16 + m16;
  int qcbase = blockIdx.y * 64 + wv * 16 + quad * 4;

  size_t qoff = (size_t)(b * Tt + qfrow) * sq + oq + hd * 64;
  f16x8 qh0 = *reinterpret_cast<const f16x8*>(Qh + qoff + quad * 8);
  f16x8 qh1 = *reinterpret_cast<const f16x8*>(Qh + qoff + 32 + quad * 8);
  f16x8 ql0 = *reinterpret_cast<const f16x8*>(Ql + qoff + quad * 8);
  f16x8 ql1 = *reinterpret_cast<const f16x8*>(Ql + qoff + 32 + quad * 8);

  f32x4 Om[4], Oc[4];
#pragma unroll
  for (int c = 0; c < 4; c++) {
    Om[c] = (f32x4){0.f, 0.f, 0.f, 0.f};
    Oc[c] = (f32x4){0.f, 0.f, 0.f, 0.f};
  }
  float mr[4] = {-1e30f, -1e30f, -1e30f, -1e30f};
  float lrw[4] = {0.f, 0.f, 0.f, 0.f};

  int NT = causal ? (blockIdx.y * 2 + 2) : (nK >> 5);
  int myNT = causal ? (((blockIdx.y * 64 + wv * 16 + 15) >> 5) + 1) : NT;

  int rk = t >> 3, gs = t & 7, gsrc = gs ^ (rk & 7);
  int rv = t & 31, gv = t >> 5;

  for (int kt = 0; kt < NT; ++kt) {
    __syncthreads();
    {
      size_t krow = (size_t)(b * 1024 + kt * 32 + rk) * sk + ok + hd * 64 + gsrc * 8;
      *reinterpret_cast<f16x8*>(&Ksh[t * 8]) = *reinterpret_cast<const f16x8*>(Kh + krow);
      *reinterpret_cast<f16x8*>(&Ksl[t * 8]) = *reinterpret_cast<const f16x8*>(Kl + krow);
      size_t vrow = (size_t)(b * 1024 + kt * 32 + rv) * sv + ov + hd * 64 + gv * 8;
      f16x8 vh8 = *reinterpret_cast<const f16x8*>(Vh + vrow);
      f16x8 vl8 = *reinterpret_cast<const f16x8*>(Vl + vrow);
#pragma unroll
      for (int i = 0; i < 8; i++) {
        Vth[(gv * 8 + i) * 32 + rv] = vh8[i];
        Vtl[(gv * 8 + i) * 32 + rv] = vl8[i];
      }
    }
    __syncthreads();

    if (kt < myNT) {
      f32x4 S0m = (f32x4){0.f, 0.f, 0.f, 0.f}, S0c = S0m, S1m = S0m, S1c = S0m;
      {
        int key0 = m16, key1 = 16 + m16;
        int g0a = (quad) ^ (key0 & 7), g0b = (4 + quad) ^ (key0 & 7);
        int g1a = (quad) ^ (key1 & 7), g1b = (4 + quad) ^ (key1 & 7);
        f16x8 kh0a = *reinterpret_cast<const f16x8*>(&Ksh[key0 * 64 + g0a * 8]);
        f16x8 kh0b = *reinterpret_cast<const f16x8*>(&Ksh[key0 * 64 + g0b * 8]);
        f16x8 kl0a = *reinterpret_cast<const f16x8*>(&Ksl[key0 * 64 + g0a * 8]);
        f16x8 kl0b = *reinterpret_cast<const f16x8*>(&Ksl[key0 * 64 + g0b * 8]);
        S0m = __builtin_amdgcn_mfma_f32_16x16x32_f16(qh0, kh0a, S0m, 0, 0, 0);
        S0m = __builtin_amdgcn_mfma_f32_16x16x32_f16(qh1, kh0b, S0m, 0, 0, 0);
        S0c = __builtin_amdgcn_mfma_f32_16x16x32_f16(qh0, kl0a, S0c, 0, 0, 0);
        S0c = __builtin_amdgcn_mfma_f32_16x16x32_f16(qh1, kl0b, S0c, 0, 0, 0);
        S0c = __builtin_amdgcn_mfma_f32_16x16x32_f16(ql0, kh0a, S0c, 0, 0, 0);
        S0c = __builtin_amdgcn_mfma_f32_16x16x32_f16(ql1, kh0b, S0c, 0, 0, 0);
        f16x8 kh1a = *reinterpret_cast<const f16x8*>(&Ksh[key1 * 64 + g1a * 8]);
        f16x8 kh1b = *reinterpret_cast<const f16x8*>(&Ksh[key1 * 64 + g1b * 8]);
        f16x8 kl1a = *reinterpret_cast<const f16x8*>(&Ksl[key1 * 64 + g1a * 8]);
        f16x8 kl1b = *reinterpret_cast<const f16x8*>(&Ksl[key1 * 64 + g1b * 8]);
        S1m = __builtin_amdgcn_mfma_f32_16x16x32_f16(qh0, kh1a, S1m, 0, 0, 0);
        S1m = __builtin_amdgcn_mfma_f32_16x16x32_f16(qh1, kh1b, S1m, 0, 0, 0);
        S1c = __builtin_amdgcn_mfma_f32_16x16x32_f16(qh0, kl1a, S1c, 0, 0, 0);
        S1c = __builtin_amdgcn_mfma_f32_16x16x32_f16(qh1, kl1b, S1c, 0, 0, 0);
        S1c = __builtin_amdgcn_mfma_f32_16x16x32_f16(ql0, kh1a, S1c, 0, 0, 0);
        S1c = __builtin_amdgcn_mfma_f32_16x16x32_f16(ql1, kh1b, S1c, 0, 0, 0);
      }
      float S0[4], S1[4];
      int key0 = kt * 32 + m16, key1 = kt * 32 + 16 + m16;
      int am0 = amask ? amask[b * nK + key0] : 1;
      int am1 = amask ? amask[b * nK + key1] : 1;
#pragma unroll
      for (int reg = 0; reg < 4; reg++) {
        int qr = qcbase + reg;
        bool ok0 = am0 && (!causal || key0 <= qr);
        bool ok1 = am1 && (!causal || key1 <= qr);
        S0[reg] = ok0 ? (S0m[reg] + S0c[reg] * ILOSC) * 0.125f : -1e9f;
        S1[reg] = ok1 ? (S1m[reg] + S1c[reg] * ILOSC) * 0.125f : -1e9f;
      }
      float mt[4], al4[4], rs[4];
#pragma unroll
      for (int reg = 0; reg < 4; reg++) mt[reg] = fmaxf(S0[reg], S1[reg]);
#pragma unroll
      for (int off = 1; off < 16; off <<= 1)
#pragma unroll
        for (int reg = 0; reg < 4; reg++) mt[reg] = fmaxf(mt[reg], __shfl_xor(mt[reg], off, 64));
#pragma unroll
      for (int reg = 0; reg < 4; reg++) {
        float mn = fmaxf(mr[reg], mt[reg]);
        al4[reg] = expf(mr[reg] - mn);
        mr[reg] = mn;
        S0[reg] = expf(S0[reg] - mn);
        S1[reg] = expf(S1[reg] - mn);
        rs[reg] = S0[reg] + S1[reg];
      }
#pragma unroll
      for (int off = 1; off < 16; off <<= 1)
#pragma unroll
        for (int reg = 0; reg < 4; reg++) rs[reg] += __shfl_xor(rs[reg], off, 64);
#pragma unroll
      for (int reg = 0; reg < 4; reg++) {
        lrw[reg] = lrw[reg] * al4[reg] + rs[reg];
#pragma unroll
        for (int c = 0; c < 4; c++) { Om[c][reg] *= al4[reg]; Oc[c][reg] *= al4[reg]; }
        int prow = wv * 16 + quad * 4 + reg;
        f16 ph, pl;
        fsplit(S0[reg], ph, pl);
        Psh[prow * 32 + m16] = ph; Psl[prow * 32 + m16] = pl;
        fsplit(S1[reg], ph, pl);
        Psh[prow * 32 + 16 + m16] = ph; Psl[prow * 32 + 16 + m16] = pl;
      }
      __builtin_amdgcn_sched_barrier(0);
      f16x8 pah = *reinterpret_cast<const f16x8*>(&Psh[(wv * 16 + m16) * 32 + quad * 8]);
      f16x8 pal = *reinterpret_cast<const f16x8*>(&Psl[(wv * 16 + m16) * 32 + quad * 8]);
#pragma unroll
      for (int c = 0; c < 4; c++) {
        f16x8 vbh = *reinterpret_cast<const f16x8*>(&Vth[(c * 16 + m16) * 32 + quad * 8]);
        f16x8 vbl = *reinterpret_cast<const f16x8*>(&Vtl[(c * 16 + m16) * 32 + quad * 8]);
        Om[c] = __builtin_amdgcn_mfma_f32_16x16x32_f16(pah, vbh, Om[c], 0, 0, 0);
        Oc[c] = __builtin_amdgcn_mfma_f32_16x16x32_f16(pah, vbl, Oc[c], 0, 0, 0);
        Oc[c] = __builtin_amdgcn_mfma_f32_16x16x32_f16(pal, vbh, Oc[c], 0, 0, 0);
      }
    }
  }
#pragma unroll
  for (int reg = 0; reg < 4; reg++) {
    int qr = qcbase + reg;
    float inv = 1.f / lrw[reg];
#pragma unroll
    for (int c = 0; c < 4; c++) {
      float o = (Om[c][reg] + Oc[c][reg] * ILOSC) * inv;
      f16 hh, ll; fsplit(o, hh, ll);
      size_t oo = (size_t)(b * Tt + qr) * Dd + hd * 64 + c * 16 + m16;
      Oh[oo] = hh;
      Ol[oo] = ll;
    }
  }
}

// ---------------------------------------------------------------------------
__global__ __launch_bounds__(256)
void add_ln_kernel(float* __restrict__ Y, f16* __restrict__ Yh, f16* __restrict__ Yl,
                   const float* __restrict__ Aadd,
                   const float* __restrict__ g, const float* __restrict__ bb) {
  int tid = threadIdx.x;
  size_t base = (size_t)blockIdx.x * Dd;
  __shared__ float red[256];
  __shared__ float mu_s, rs_s;
  float x0 = Y[base + tid] + Aadd[base + tid];
  float x1 = Y[base + 256 + tid] + Aadd[base + 256 + tid];
  red[tid] = x0 + x1; __syncthreads();
  for (int s2 = 128; s2 > 0; s2 >>= 1) { if (tid < s2) red[tid] += red[tid + s2]; __syncthreads(); }
  if (tid == 0) mu_s = red[0] / (float)Dd;
  __syncthreads();
  float mu = mu_s;
  float d0 = x0 - mu, d1 = x1 - mu;
  red[tid] = d0 * d0 + d1 * d1; __syncthreads();
  for (int s2 = 128; s2 > 0; s2 >>= 1) { if (tid < s2) red[tid] += red[tid + s2]; __syncthreads(); }
  if (tid == 0) rs_s = rsqrtf(red[0] / (float)Dd + EPSF);
  __syncthreads();
  float rs = rs_s;
  float o0 = d0 * rs * g[tid] + bb[tid];
  float o1 = d1 * rs * g[256 + tid] + bb[256 + tid];
  f16 h, l;
  Y[base + tid] = o0; fsplit(o0, h, l); Yh[base + tid] = h; Yl[base + tid] = l;
  Y[base + 256 + tid] = o1; fsplit(o1, h, l); Yh[base + 256 + tid] = h; Yl[base + 256 + tid] = l;
}

__global__ __launch_bounds__(256)
void combine_ln_kernel(float* __restrict__ Y, f16* __restrict__ Yh, f16* __restrict__ Yl,
                       const float* __restrict__ pout, const float* __restrict__ pout2,
                       const int* __restrict__ slot,
                       const float* __restrict__ g, const float* __restrict__ bb) {
  int tid = threadIdx.x;
  int m = blockIdx.x;
  size_t base = (size_t)m * Dd;
  int s0 = slot[m * 2 + 0], s1 = slot[m * 2 + 1];
  __shared__ float red[256];
  __shared__ float mu_s, rs_s;
  float x0 = Y[base + tid] + pout[(size_t)s0 * Dd + tid] + pout[(size_t)s1 * Dd + tid]
           + pout2[(size_t)s0 * Dd + tid] + pout2[(size_t)s1 * Dd + tid];
  float x1 = Y[base + 256 + tid] + pout[(size_t)s0 * Dd + 256 + tid] + pout[(size_t)s1 * Dd + 256 + tid]
           + pout2[(size_t)s0 * Dd + 256 + tid] + pout2[(size_t)s1 * Dd + 256 + tid];
  red[tid] = x0 + x1; __syncthreads();
  for (int s2 = 128; s2 > 0; s2 >>= 1) { if (tid < s2) red[tid] += red[tid + s2]; __syncthreads(); }
  if (tid == 0) mu_s = red[0] / (float)Dd;
  __syncthreads();
  float mu = mu_s;
  float d0 = x0 - mu, d1 = x1 - mu;
  red[tid] = d0 * d0 + d1 * d1; __syncthreads();
  for (int s2 = 128; s2 > 0; s2 >>= 1) { if (tid < s2) red[tid] += red[tid + s2]; __syncthreads(); }
  if (tid == 0) rs_s = rsqrtf(red[0] / (float)Dd + EPSF);
  __syncthreads();
  float rs = rs_s;
  float o0 = d0 * rs * g[tid] + bb[tid];
  float o1 = d1 * rs * g[256 + tid] + bb[256 + tid];
  f16 h, l;
  Y[base + tid] = o0; fsplit(o0, h, l); Yh[base + tid] = h; Yl[base + tid] = l;
  Y[base + 256 + tid] = o1; fsplit(o1, h, l); Yh[base + 256 + tid] = h; Yl[base + 256 + tid] = l;
}

// ---------------------------------------------------------------------------
// Router v2: zero contended atomics.
// ---------------------------------------------------------------------------
__global__ __launch_bounds__(256)
void router_kernel(const float* __restrict__ Y, const float* __restrict__ rw,
                   const float* __restrict__ rb, float* __restrict__ gates,
                   int* __restrict__ topi, int* __restrict__ part_cnt,
                   float* __restrict__ part_sumP) {
  int wv = threadIdx.x >> 6, lane = threadIdx.x & 63;
  __shared__ float wsum[4][Ee];
  __shared__ int wcnt[4][Ee];
  float w[8][Ee];
#pragma unroll
  for (int dd = 0; dd < 8; dd++) {
    const float4* rp = reinterpret_cast<const float4*>(&rw[(size_t)(dd * 64 + lane) * Ee]);
    float4 a = rp[0], b4 = rp[1];
    w[dd][0] = a.x; w[dd][1] = a.y; w[dd][2] = a.z; w[dd][3] = a.w;
    w[dd][4] = b4.x; w[dd][5] = b4.y; w[dd][6] = b4.z; w[dd][7] = b4.w;
  }
  float rbv[Ee];
#pragma unroll
  for (int e = 0; e < Ee; e++) rbv[e] = rb[e];

  float psum[Ee]; int pcnt[Ee];
#pragma unroll
  for (int e = 0; e < Ee; e++) { psum[e] = 0.f; pcnt[e] = 0; }

  int m0 = blockIdx.x * 32 + wv * 8;
  for (int j = 0; j < 8; j++) {
    int m = m0 + j;
    const float* yr = Y + (size_t)m * Dd;
    float yv[8];
#pragma unroll
    for (int dd = 0; dd < 8; dd++) yv[dd] = yr[dd * 64 + lane];
    float acc[Ee];
#pragma unroll
    for (int e = 0; e < Ee; e++) acc[e] = 0.f;
#pragma unroll
    for (int dd = 0; dd < 8; dd++)
#pragma unroll
      for (int e = 0; e < Ee; e++) acc[e] += yv[dd] * w[dd][e];
#pragma unroll
    for (int off = 32; off; off >>= 1)
#pragma unroll
      for (int e = 0; e < Ee; e++) acc[e] += __shfl_xor(acc[e], off, 64);
    if (lane == 0) {
      float pv[Ee];
      float mx = -1e30f;
#pragma unroll
      for (int e = 0; e < Ee; e++) { pv[e] = acc[e] + rbv[e]; mx = fmaxf(mx, pv[e]); }
      float ssum = 0.f;
#pragma unroll
      for (int e = 0; e < Ee; e++) { pv[e] = expf(pv[e] - mx); ssum += pv[e]; }
      float invs = 1.f / ssum;
#pragma unroll
      for (int e = 0; e < Ee; e++) { pv[e] *= invs; psum[e] += pv[e]; }
      int i1 = 0;
#pragma unroll
      for (int e = 1; e < Ee; e++) if (pv[e] > pv[i1]) i1 = e;
      int i2 = (i1 == 0) ? 1 : 0;
#pragma unroll
      for (int e = 0; e < Ee; e++) if (e != i1 && pv[e] > pv[i2]) i2 = e;
      float gs = pv[i1] + pv[i2];
      gates[m * 2 + 0] = pv[i1] / gs;
      gates[m * 2 + 1] = pv[i2] / gs;
      topi[m * 2 + 0] = i1;
      topi[m * 2 + 1] = i2;
#pragma unroll
      for (int e = 0; e < Ee; e++) pcnt[e] += (e == i1) + (e == i2);
    }
  }
  if (lane == 0) {
#pragma unroll
    for (int e = 0; e < Ee; e++) { wsum[wv][e] = psum[e]; wcnt[wv][e] = pcnt[e]; }
  }
  __syncthreads();
  if (threadIdx.x < Ee) {
    int e = threadIdx.x;
    float s = wsum[0][e] + wsum[1][e] + wsum[2][e] + wsum[3][e];
    int c = wcnt[0][e] + wcnt[1][e] + wcnt[2][e] + wcnt[3][e];
    part_sumP[blockIdx.x * Ee + e] = s;
    part_cnt[blockIdx.x * Ee + e] = c;
  }
}

__global__ void prefix_lb_kernel(const int* __restrict__ part_cnt,
                                 const float* __restrict__ part_sumP,
                                 int* __restrict__ cnt, int* __restrict__ offs,
                                 int* __restrict__ fill, float* __restrict__ lb_acc) {
  __shared__ int sc[Ee];
  __shared__ float ss[Ee];
  int t = threadIdx.x;
  if (t < Ee) {
    int c = 0; float s = 0.f;
    for (int b2 = 0; b2 < RBLK; b2++) { c += part_cnt[b2 * Ee + t]; s += part_sumP[b2 * Ee + t]; }
    sc[t] = c; ss[t] = s;
    cnt[t] = c; fill[t] = 0;
  }
  __syncthreads();
  if (t == 0) {
    int run = 0;
    float lb = 0.f;
    for (int e = 0; e < Ee; e++) {
      offs[e] = run; run += sc[e];
      lb += ((float)sc[e] * IMm) * (ss[e] * IMm);
    }
    *lb_acc += (float)Ee * lb;
  }
}

__global__ __launch_bounds__(256)
void scatter_kernel(const int* __restrict__ topi, const float* __restrict__ gates,
                    const int* __restrict__ offs, int* __restrict__ fill,
                    int* __restrict__ pair_tok, float* __restrict__ pair_gate,
                    int* __restrict__ slot) {
  __shared__ int lcnt[Ee];
  __shared__ int lbase[Ee];
  int t = threadIdx.x;
  int m = blockIdx.x * 256 + t;
  if (t < Ee) lcnt[t] = 0;
  __syncthreads();
  int e0 = topi[m * 2 + 0], e1 = topi[m * 2 + 1];
  float g0 = gates[m * 2 + 0], g1 = gates[m * 2 + 1];
  int p0 = atomicAdd(&lcnt[e0], 1);
  int p1 = atomicAdd(&lcnt[e1], 1);
  __syncthreads();
  if (t < Ee) lbase[t] = atomicAdd(&fill[t], lcnt[t]);
  __syncthreads();
  int i0 = offs[e0] + lbase[e0] + p0;
  int i1 = offs[e1] + lbase[e1] + p1;
  pair_tok[i0] = m; pair_gate[i0] = g0; slot[m * 2 + 0] = i0;
  pair_tok[i1] = m; pair_gate[i1] = g1; slot[m * 2 + 1] = i1;
}

__global__ void init_lb_kernel(float* lb_acc) {
  if (threadIdx.x == 0) *lb_acc = 0.f;
}

__global__ void finalize_kernel(const float* __restrict__ Y,
                                const float* __restrict__ lb_acc,
                                float* __restrict__ out) {
  size_t i = (size_t)blockIdx.x * 256 + threadIdx.x;
  const size_t n = (size_t)Mm * Dd;
  if (i < n) out[i] = Y[i];
  if (i == 0) out[n] = *lb_acc;
}

// ---------------------------------------------------------------------------
extern "C" void kernel_launch(void* const* d_in, const int* in_sizes, int n_in,
                              void* d_out, int out_size, void* d_ws, size_t ws_size,
                              hipStream_t stream) {
  const int*   ids   = (const int*)d_in[0];
  const float* enc   = (const float*)d_in[1];
  const int*   amask = (const int*)d_in[2];
  const float* emb   = (const float*)d_in[3];
  const float* pos   = (const float*)d_in[4];
  const float* sa_w  = (const float*)d_in[5];
  const float* sa_b  = (const float*)d_in[6];
  const float* ca_w  = (const float*)d_in[7];
  const float* ca_b  = (const float*)d_in[8];
  const float* ln_g  = (const float*)d_in[9];
  const float* ln_b  = (const float*)d_in[10];
  const float* rw    = (const float*)d_in[11];
  const float* rb    = (const float*)d_in[12];
  const float* ew1   = (const float*)d_in[13];
  const float* eb1   = (const float*)d_in[14];
  const float* ew2   = (const float*)d_in[15];
  const float* eb2   = (const float*)d_in[16];
  float* out = (float*)d_out;

  char* p = (char*)d_ws;
  auto alloc = [&](size_t bytes) { void* r = p; p += (bytes + 255) & ~(size_t)255; return r; };
  float* y    = (float*)alloc((size_t)Mm * Dd * 4);
  float* proj = (float*)alloc((size_t)Mm * Dd * 4);
  float* pout = (float*)alloc((size_t)2 * NPp * Dd * 4);   // 2 split-K slices
  f16* yh   = (f16*)alloc((size_t)Mm * Dd * 2);
  f16* yl   = (f16*)alloc((size_t)Mm * Dd * 2);
  f16* ench = (f16*)alloc((size_t)Mm * Dd * 2);
  f16* encl = (f16*)alloc((size_t)Mm * Dd * 2);
  f16* qkvh = (f16*)alloc((size_t)Mm * 1536 * 2);
  f16* qkvl = (f16*)alloc((size_t)Mm * 1536 * 2);
  f16* qch  = (f16*)alloc((size_t)Mm * Dd * 2);
  f16* qcl  = (f16*)alloc((size_t)Mm * Dd * 2);
  f16* atth = (f16*)alloc((size_t)Mm * Dd * 2);
  f16* attl = (f16*)alloc((size_t)Mm * Dd * 2);
  f16* ckvh = (f16*)alloc((size_t)Mm * 1024 * 2);
  f16* ckvl = (f16*)alloc((size_t)Mm * 1024 * 2);
  f16* moeh = (f16*)alloc((size_t)NPp * FFf * 2);
  f16* moel = (f16*)alloc((size_t)NPp * FFf * 2);
  f16* saTh = (f16*)alloc((size_t)Ll * 4 * DD_ * 2);
  f16* saTl = (f16*)alloc((size_t)Ll * 4 * DD_ * 2);
  f16* caTh = (f16*)alloc((size_t)Ll * 4 * DD_ * 2);
  f16* caTl = (f16*)alloc((size_t)Ll * 4 * DD_ * 2);
  f16* w1Th = (f16*)alloc((size_t)Ee * Dd * FFf * 2);
  f16* w1Tl = (f16*)alloc((size_t)Ee * Dd * FFf * 2);
  f16* w2Th = (f16*)alloc((size_t)Ee * Dd * FFf * 2);
  f16* w2Tl = (f16*)alloc((size_t)Ee * Dd * FFf * 2);
  float* gates     = (float*)alloc((size_t)Mm * 2 * 4);
  float* pair_gate = (float*)alloc((size_t)NPp * 4);
  float* part_sumP = (float*)alloc((size_t)RBLK * Ee * 4);
  float* lb_acc    = (float*)alloc(4);
  int* topi     = (int*)alloc((size_t)Mm * 2 * 4);
  int* pair_tok = (int*)alloc((size_t)NPp * 4);
  int* slot     = (int*)alloc((size_t)Mm * 2 * 4);
  int* part_cnt = (int*)alloc((size_t)RBLK * Ee * 4);
  int* cnt      = (int*)alloc(Ee * 4);
  int* offs     = (int*)alloc(Ee * 4);
  int* fill     = (int*)alloc(Ee * 4);
  float* pout2 = pout + (size_t)NPp * Dd;

  init_lb_kernel<<<1, 64, 0, stream>>>(lb_acc);
  embed_kernel<<<Mm, 256, 0, stream>>>(ids, emb, pos, y, yh, yl);
  cvt_split_kernel<<<(Mm * Dd) / 1024, 256, 0, stream>>>(enc, ench, encl);
  transpose_split<<<dim3(16, 16, 16), 256, 0, stream>>>(sa_w, saTh, saTl, Dd, Dd);
  transpose_split<<<dim3(16, 16, 16), 256, 0, stream>>>(ca_w, caTh, caTl, Dd, Dd);

  dim3 gAttn(Bb * Hh, Tt / 64);

  for (int i = 0; i < Ll; i++) {
    transpose_split<<<dim3(64, 16, 8), 256, 0, stream>>>(ew1 + (size_t)i * Ee * Dd * FFf, w1Th, w1Tl, Dd, FFf);
    transpose_split<<<dim3(16, 64, 8), 256, 0, stream>>>(ew2 + (size_t)i * Ee * FFf * Dd, w2Th, w2Tl, FFf, Dd);

    const f16* saThl = saTh + (size_t)i * 4 * DD_;
    const f16* saTll = saTl + (size_t)i * 4 * DD_;
    const f16* caThl = caTh + (size_t)i * 4 * DD_;
    const f16* caTll = caTl + (size_t)i * 4 * DD_;
    const float* sabl = sa_b + (size_t)i * 4 * Dd;
    const float* cabl = ca_b + (size_t)i * 4 * Dd;

    // cross K,V (fused N=1024)
    mm128<false, true, false, false, 1><<<dim3(8, 16, 1), 256, 0, stream>>>(
        ench, encl, Dd, caThl + DD_, caTll + DD_, cabl + Dd,
        nullptr, ckvh, ckvl, 1024, Mm, 1024, Dd, nullptr, nullptr, nullptr, nullptr);
    // self QKV (fused N=1536)
    mm128<false, true, false, false, 1><<<dim3(12, 16, 1), 256, 0, stream>>>(
        yh, yl, Dd, saThl, saTll, sabl,
        nullptr, qkvh, qkvl, 1536, Mm, 1536, Dd, nullptr, nullptr, nullptr, nullptr);
    // self attention
    attn_mfma<<<gAttn, 256, 0, stream>>>(qkvh, qkvl, 1536, 0, qkvh, qkvl, 1536, 512,
                                         qkvh, qkvl, 1536, 1024, atth, attl, amask, 1, Tt);
    // self out-proj
    mm128<false, false, false, false, 1><<<dim3(4, 16, 1), 256, 0, stream>>>(
        atth, attl, Dd, saThl + 3 * DD_, saTll + 3 * DD_, sabl + 3 * Dd,
        proj, nullptr, nullptr, Dd, Mm, Dd, Dd, nullptr, nullptr, nullptr, nullptr);
    add_ln_kernel<<<Mm, 256, 0, stream>>>(y, yh, yl, proj,
                                          ln_g + (size_t)(i * 3 + 0) * Dd, ln_b + (size_t)(i * 3 + 0) * Dd);
    // cross Q
    mm128<false, true, false, false, 1><<<dim3(4, 16, 1), 256, 0, stream>>>(
        yh, yl, Dd, caThl, caTll, cabl,
        nullptr, qch, qcl, Dd, Mm, Dd, Dd, nullptr, nullptr, nullptr, nullptr);
    // cross attention
    attn_mfma<<<gAttn, 256, 0, stream>>>(qch, qcl, Dd, 0, ckvh, ckvl, 1024, 0,
                                         ckvh, ckvl, 1024, 512, atth, attl, nullptr, 0, Ss);
    // cross out-proj
    mm128<false, false, false, false, 1><<<dim3(4, 16, 1), 256, 0, stream>>>(
        atth, attl, Dd, caThl + 3 * DD_, caTll + 3 * DD_, cabl + 3 * Dd,
        proj, nullptr, nullptr, Dd, Mm, Dd, Dd, nullptr, nullptr, nullptr, nullptr);
    add_ln_kernel<<<Mm, 256, 0, stream>>>(y, yh, yl, proj,
                                          ln_g + (size_t)(i * 3 + 1) * Dd, ln_b + (size_t)(i * 3 + 1) * Dd);
    // MoE (atomic-free router)
    router_kernel<<<RBLK, 256, 0, stream>>>(y, rw + (size_t)i * Dd * Ee, rb + (size_t)i * Ee,
                                            gates, topi, part_cnt, part_sumP);
    prefix_lb_kernel<<<1, 64, 0, stream>>>(part_cnt, part_sumP, cnt, offs, fill, lb_acc);
    scatter_kernel<<<Mm / 256, 256, 0, stream>>>(topi, gates, offs, fill, pair_tok, pair_gate, slot);
    mm128<true, true, true, false, 1><<<dim3(16, 32, 8), 256, 0, stream>>>(
        yh, yl, Dd, w1Th, w1Tl, eb1 + (size_t)i * Ee * FFf,
        nullptr, moeh, moel, FFf, NPp, FFf, Dd, pair_tok, nullptr, offs, cnt);
    // w2: split-K x2 via separate output buffers (no atomics)
    mm128<false, false, false, true, 2><<<dim3(4, 32, Ee * 2), 256, 0, stream>>>(
        moeh, moel, FFf, w2Th, w2Tl, eb2 + (size_t)i * Ee * Dd,
        pout, nullptr, nullptr, Dd, NPp, Dd, FFf, nullptr, pair_gate, offs, cnt);
    combine_ln_kernel<<<Mm, 256, 0, stream>>>(y, yh, yl, pout, pout2, slot,
                                              ln_g + (size_t)(i * 3 + 2) * Dd, ln_b + (size_t)(i * 3 + 2) * Dd);
  }

  finalize_kernel<<<(int)(((size_t)Mm * Dd + 256) / 256) + 1, 256, 0, stream>>>(y, lb_acc, out);
}

// Round 4
// 2425.831 us; speedup vs baseline: 1.1842x; 1.0048x over previous
//
#include <hip/hip_runtime.h>
#include <math.h>

#define Bb 2
#define Tt 1024
#define Ss 1024
#define Dd 512
#define Hh 8
#define Ll 4
#define Ee 8
#define FFf 2048
#define Mm 2048
#define NPp 4096
#define EPSF 1e-5f
#define DD_ (Dd*Dd)
#define LOSC 1024.0f
#define ILOSC (1.0f/1024.0f)
#define RBLK 64   // router blocks (Mm/32)
#define IMm (1.0f/(float)Mm)

typedef _Float16 f16;
typedef __attribute__((ext_vector_type(8))) _Float16 f16x8;
typedef __attribute__((ext_vector_type(4))) _Float16 f16x4;
typedef __attribute__((ext_vector_type(4))) float f32x4;

// split: x = hi + lo/1024 (lo pre-scaled by 1024 so it stays fp16-normal)
__device__ __forceinline__ void fsplit(float x, f16& h, f16& l) {
  h = (f16)x;
  l = (f16)((x - (float)h) * LOSC);
}

__device__ __forceinline__ void load16(const void* g, void* l) {
  __builtin_amdgcn_global_load_lds(
      (const __attribute__((address_space(1))) void*)g,
      (__attribute__((address_space(3))) void*)l, 16, 0, 0);
}

// ---------------------------------------------------------------------------
__global__ void embed_kernel(const int* __restrict__ ids,
                             const float* __restrict__ emb,
                             const float* __restrict__ pos,
                             float* __restrict__ Y,
                             f16* __restrict__ Yh, f16* __restrict__ Yl) {
  int m = blockIdx.x;
  int t = m % Tt;
  int id = ids[m];
  for (int d = threadIdx.x; d < Dd; d += 256) {
    float v = emb[(size_t)id * Dd + d] + pos[(size_t)t * Dd + d];
    Y[(size_t)m * Dd + d] = v;
    f16 h, l; fsplit(v, h, l);
    Yh[(size_t)m * Dd + d] = h;
    Yl[(size_t)m * Dd + d] = l;
  }
}

__global__ void cvt_split_kernel(const float* __restrict__ src,
                                 f16* __restrict__ dh, f16* __restrict__ dl) {
  size_t i = ((size_t)blockIdx.x * 256 + threadIdx.x) * 4;
  float4 v = *reinterpret_cast<const float4*>(&src[i]);
  float a[4] = {v.x, v.y, v.z, v.w};
#pragma unroll
  for (int j = 0; j < 4; j++) { f16 h, l; fsplit(a[j], h, l); dh[i + j] = h; dl[i + j] = l; }
}

// ---------------------------------------------------------------------------
// Batched transpose+split: src[z]=[Kd,Nd] fp32 -> dstH/dstL[z]=[Nd,Kd] fp16
// ---------------------------------------------------------------------------
__global__ __launch_bounds__(256)
void transpose_split(const float* __restrict__ src,
                     f16* __restrict__ dstH, f16* __restrict__ dstL,
                     int Kd, int Nd) {
  __shared__ float Tl[32][33];
  size_t zo = (size_t)blockIdx.z * Kd * Nd;
  int k0 = blockIdx.y * 32, n0 = blockIdx.x * 32;
  int t = threadIdx.x;
  int r = t >> 3, c = t & 7;
  float4 v = *reinterpret_cast<const float4*>(&src[zo + (size_t)(k0 + r) * Nd + n0 + c * 4]);
  Tl[r][c * 4 + 0] = v.x; Tl[r][c * 4 + 1] = v.y;
  Tl[r][c * 4 + 2] = v.z; Tl[r][c * 4 + 3] = v.w;
  __syncthreads();
  int nl = t >> 3, kq = t & 7;
  f16x4 hv, lv;
#pragma unroll
  for (int i = 0; i < 4; i++) {
    f16 h, l; fsplit(Tl[kq * 4 + i][nl], h, l);
    hv[i] = h; lv[i] = l;
  }
  size_t o = zo + (size_t)(n0 + nl) * Kd + k0 + kq * 4;
  *reinterpret_cast<f16x4*>(&dstH[o]) = hv;
  *reinterpret_cast<f16x4*>(&dstL[o]) = lv;
}

// ---------------------------------------------------------------------------
// 128x128 split-fp16 MFMA GEMM (3-product), 3-stage LDS ring with counted
// vmcnt (never drains to 0 in steady state; 16-24 loads always in flight).
// A hi/lo [*,K], B hi/lo [N,K].
// KS>1: split-K over blockIdx.z (z = expert*KS + kslice); slice ks writes
// plain stores into Cf + ks*Mtot*ldc (bias in slice 0 only; no atomics).
// LDS slot-XOR swizzle: linear global_load_lds dest, pre-swizzled global
// source slot (cc ^ ((rr>>1)&3)), swizzled ds_read slot (quad ^ ((m16>>1)&3)).
// ---------------------------------------------------------------------------
template <bool GATHER, bool OSPLIT, bool RELU, bool GATE, int KS>
__global__ __launch_bounds__(256)
void mm128(const f16* __restrict__ Ah_, const f16* __restrict__ Al_, int lda,
           const f16* __restrict__ Bh_, const f16* __restrict__ Bl_,
           const float* __restrict__ bias,
           float* __restrict__ Cf, f16* __restrict__ Ch, f16* __restrict__ Cl, int ldc,
           int Mtot, int N, int K,
           const int* __restrict__ tok, const float* __restrict__ gate,
           const int* __restrict__ offs, const int* __restrict__ cnt) {
  __shared__ f16 Ash[3][128 * 32];
  __shared__ f16 Asl[3][128 * 32];
  __shared__ f16 Bsh[3][128 * 32];
  __shared__ f16 Bsl[3][128 * 32];
  int zz = blockIdx.z;
  int e  = (KS > 1) ? (zz / KS) : zz;
  int ks = (KS > 1) ? (zz % KS) : 0;
  int base = 0, ne = Mtot;
  if (offs) { base = offs[e]; ne = cnt[e]; }
  int m0 = blockIdx.y * 128;
  if (m0 >= ne) return;
  int rem = ne - m0;
  Bh_ += (size_t)e * N * K;
  Bl_ += (size_t)e * N * K;
  bias += (size_t)e * N;
  if (KS > 1) Cf += (size_t)ks * (size_t)Mtot * (size_t)ldc;

  int t = threadIdx.x;
  int rr = t >> 2, cc = t & 3;
  int csw = cc ^ ((rr >> 1) & 3);   // pre-swizzled source slot
  int gr0 = base + m0 + rr;      if (gr0 > Mtot - 1) gr0 = Mtot - 1;
  int gr1 = base + m0 + rr + 64; if (gr1 > Mtot - 1) gr1 = Mtot - 1;
  int arow0 = GATHER ? tok[gr0] : gr0;
  int arow1 = GATHER ? tok[gr1] : gr1;
  size_t aoff0 = (size_t)arow0 * lda + csw * 8;
  size_t aoff1 = (size_t)arow1 * lda + csw * 8;
  size_t boff0 = (size_t)(blockIdx.x * 128 + rr) * K + csw * 8;
  size_t boff1 = (size_t)(blockIdx.x * 128 + rr + 64) * K + csw * 8;

  int lane = t & 63, wv = t >> 6;
  int quad = lane >> 4, m16 = lane & 15;
  int sw = quad ^ ((m16 >> 1) & 3);  // swizzled read slot
  int wm = (wv >> 1) * 64, wn = (wv & 1) * 64;

  f32x4 accm[4][4], accc[4][4];
#pragma unroll
  for (int i = 0; i < 4; i++)
#pragma unroll
    for (int j = 0; j < 4; j++) {
      accm[i][j] = (f32x4){0.f, 0.f, 0.f, 0.f};
      accc[i][j] = (f32x4){0.f, 0.f, 0.f, 0.f};
    }

  int kper = K / KS;
  int kbeg = ks * kper;
  int nt = kper >> 5;

  auto STAGE = [&](int bf, int kc) {
    load16(Ah_ + aoff0 + kc, &Ash[bf][t * 8]);
    load16(Ah_ + aoff1 + kc, &Ash[bf][2048 + t * 8]);
    load16(Al_ + aoff0 + kc, &Asl[bf][t * 8]);
    load16(Al_ + aoff1 + kc, &Asl[bf][2048 + t * 8]);
    load16(Bh_ + boff0 + kc, &Bsh[bf][t * 8]);
    load16(Bh_ + boff1 + kc, &Bsh[bf][2048 + t * 8]);
    load16(Bl_ + boff0 + kc, &Bsl[bf][t * 8]);
    load16(Bl_ + boff1 + kc, &Bsl[bf][2048 + t * 8]);
  };

  // prologue: drain (make vmcnt counting exact), stage buffers 0 and 1
  asm volatile("s_waitcnt vmcnt(0)" ::: "memory");
  STAGE(0, kbeg);
  STAGE(1, kbeg + 32);

  int cur = 0;
  for (int tt = 0; tt < nt; ++tt) {
    if (tt + 2 < nt) {
      int st = (cur >= 1) ? cur - 1 : 2;   // (cur+2)%3
      STAGE(st, kbeg + (tt + 2) * 32);
      asm volatile("s_waitcnt vmcnt(16)" ::: "memory");  // stage tt landed
    } else if (tt + 2 == nt) {
      asm volatile("s_waitcnt vmcnt(8)" ::: "memory");
    } else {
      asm volatile("s_waitcnt vmcnt(0)" ::: "memory");
    }
    __builtin_amdgcn_s_barrier();   // all waves' stage-tt loads landed
    f16x8 ah[4], al[4];
#pragma unroll
    for (int i = 0; i < 4; i++) {
      ah[i] = *reinterpret_cast<const f16x8*>(&Ash[cur][(wm + i * 16 + m16) * 32 + sw * 8]);
      al[i] = *reinterpret_cast<const f16x8*>(&Asl[cur][(wm + i * 16 + m16) * 32 + sw * 8]);
    }
#pragma unroll
    for (int j = 0; j < 4; j++) {
      f16x8 bh = *reinterpret_cast<const f16x8*>(&Bsh[cur][(wn + j * 16 + m16) * 32 + sw * 8]);
      f16x8 bl = *reinterpret_cast<const f16x8*>(&Bsl[cur][(wn + j * 16 + m16) * 32 + sw * 8]);
#pragma unroll
      for (int i = 0; i < 4; i++) {
        accm[i][j] = __builtin_amdgcn_mfma_f32_16x16x32_f16(ah[i], bh, accm[i][j], 0, 0, 0);
        accc[i][j] = __builtin_amdgcn_mfma_f32_16x16x32_f16(ah[i], bl, accc[i][j], 0, 0, 0);
        accc[i][j] = __builtin_amdgcn_mfma_f32_16x16x32_f16(al[i], bh, accc[i][j], 0, 0, 0);
      }
    }
    __builtin_amdgcn_s_barrier();   // readers done before next overwrite
    cur = (cur == 2) ? 0 : cur + 1;
  }

#pragma unroll
  for (int i = 0; i < 4; i++) {
#pragma unroll
    for (int reg = 0; reg < 4; reg++) {
      int lr = wm + i * 16 + quad * 4 + reg;
      if (lr < rem) {
        size_t grow = (size_t)(base + m0 + lr);
        float gv = 1.f;
        if (GATE) gv = gate[grow];
#pragma unroll
        for (int j = 0; j < 4; j++) {
          int col = blockIdx.x * 128 + wn + j * 16 + m16;
          float bv = (KS == 1 || ks == 0) ? bias[col] : 0.f;
          float v = accm[i][j][reg] + accc[i][j][reg] * ILOSC + bv;
          if (RELU) v = fmaxf(v, 0.f);
          if (GATE) v *= gv;
          if (OSPLIT) {
            f16 h, l; fsplit(v, h, l);
            Ch[grow * ldc + col] = h;
            Cl[grow * ldc + col] = l;
          } else {
            Cf[grow * ldc + col] = v;
          }
        }
      }
    }
  }
}

// ---------------------------------------------------------------------------
// Split-fp16 MFMA flash attention. Wave = 16 queries, 32-key tiles.
// grid: (B*H, T/64)
// ---------------------------------------------------------------------------
__global__ __launch_bounds__(256)
void attn_mfma(const f16* __restrict__ Qh, const f16* __restrict__ Ql, int sq, int oq,
               const f16* __restrict__ Kh, const f16* __restrict__ Kl, int sk, int ok,
               const f16* __restrict__ Vh, const f16* __restrict__ Vl, int sv, int ov,
               f16* __restrict__ Oh, f16* __restrict__ Ol,
               const int* __restrict__ amask, int causal, int nK) {
  __shared__ f16 Ksh[32 * 64];
  __shared__ f16 Ksl[32 * 64];
  __shared__ f16 Vth[64 * 32];
  __shared__ f16 Vtl[64 * 32];
  __shared__ f16 Psh[4 * 16 * 32];
  __shared__ f16 Psl[4 * 16 * 32];

  int bh = blockIdx.x;
  int b = bh >> 3, hd = bh & 7;
  int t = threadIdx.x;
  int wv = t >> 6, lane = t & 63;
  int quad = lane >> 4, m16 = lane & 15;
  int qfrow = blockIdx.y * 64 + wv * 16 + m16;
  int qcbase = blockIdx.y * 64 + wv * 16 + quad * 4;

  size_t qoff = (size_t)(b * Tt + qfrow) * sq + oq + hd * 64;
  f16x8 qh0 = *reinterpret_cast<const f16x8*>(Qh + qoff + quad * 8);
  f16x8 qh1 = *reinterpret_cast<const f16x8*>(Qh + qoff + 32 + quad * 8);
  f16x8 ql0 = *reinterpret_cast<const f16x8*>(Ql + qoff + quad * 8);
  f16x8 ql1 = *reinterpret_cast<const f16x8*>(Ql + qoff + 32 + quad * 8);

  f32x4 Om[4], Oc[4];
#pragma unroll
  for (int c = 0; c < 4; c++) {
    Om[c] = (f32x4){0.f, 0.f, 0.f, 0.f};
    Oc[c] = (f32x4){0.f, 0.f, 0.f, 0.f};
  }
  float mr[4] = {-1e30f, -1e30f, -1e30f, -1e30f};
  float lrw[4] = {0.f, 0.f, 0.f, 0.f};

  int NT = causal ? (blockIdx.y * 2 + 2) : (nK >> 5);
  int myNT = causal ? (((blockIdx.y * 64 + wv * 16 + 15) >> 5) + 1) : NT;

  int rk = t >> 3, gs = t & 7, gsrc = gs ^ (rk & 7);
  int rv = t & 31, gv = t >> 5;

  for (int kt = 0; kt < NT; ++kt) {
    __syncthreads();
    {
      size_t krow = (size_t)(b * 1024 + kt * 32 + rk) * sk + ok + hd * 64 + gsrc * 8;
      *reinterpret_cast<f16x8*>(&Ksh[t * 8]) = *reinterpret_cast<const f16x8*>(Kh + krow);
      *reinterpret_cast<f16x8*>(&Ksl[t * 8]) = *reinterpret_cast<const f16x8*>(Kl + krow);
      size_t vrow = (size_t)(b * 1024 + kt * 32 + rv) * sv + ov + hd * 64 + gv * 8;
      f16x8 vh8 = *reinterpret_cast<const f16x8*>(Vh + vrow);
      f16x8 vl8 = *reinterpret_cast<const f16x8*>(Vl + vrow);
#pragma unroll
      for (int i = 0; i < 8; i++) {
        Vth[(gv * 8 + i) * 32 + rv] = vh8[i];
        Vtl[(gv * 8 + i) * 32 + rv] = vl8[i];
      }
    }
    __syncthreads();

    if (kt < myNT) {
      f32x4 S0m = (f32x4){0.f, 0.f, 0.f, 0.f}, S0c = S0m, S1m = S0m, S1c = S0m;
      {
        int key0 = m16, key1 = 16 + m16;
        int g0a = (quad) ^ (key0 & 7), g0b = (4 + quad) ^ (key0 & 7);
        int g1a = (quad) ^ (key1 & 7), g1b = (4 + quad) ^ (key1 & 7);
        f16x8 kh0a = *reinterpret_cast<const f16x8*>(&Ksh[key0 * 64 + g0a * 8]);
        f16x8 kh0b = *reinterpret_cast<const f16x8*>(&Ksh[key0 * 64 + g0b * 8]);
        f16x8 kl0a = *reinterpret_cast<const f16x8*>(&Ksl[key0 * 64 + g0a * 8]);
        f16x8 kl0b = *reinterpret_cast<const f16x8*>(&Ksl[key0 * 64 + g0b * 8]);
        S0m = __builtin_amdgcn_mfma_f32_16x16x32_f16(qh0, kh0a, S0m, 0, 0, 0);
        S0m = __builtin_amdgcn_mfma_f32_16x16x32_f16(qh1, kh0b, S0m, 0, 0, 0);
        S0c = __builtin_amdgcn_mfma_f32_16x16x32_f16(qh0, kl0a, S0c, 0, 0, 0);
        S0c = __builtin_amdgcn_mfma_f32_16x16x32_f16(qh1, kl0b, S0c, 0, 0, 0);
        S0c = __builtin_amdgcn_mfma_f32_16x16x32_f16(ql0, kh0a, S0c, 0, 0, 0);
        S0c = __builtin_amdgcn_mfma_f32_16x16x32_f16(ql1, kh0b, S0c, 0, 0, 0);
        f16x8 kh1a = *reinterpret_cast<const f16x8*>(&Ksh[key1 * 64 + g1a * 8]);
        f16x8 kh1b = *reinterpret_cast<const f16x8*>(&Ksh[key1 * 64 + g1b * 8]);
        f16x8 kl1a = *reinterpret_cast<const f16x8*>(&Ksl[key1 * 64 + g1a * 8]);
        f16x8 kl1b = *reinterpret_cast<const f16x8*>(&Ksl[key1 * 64 + g1b * 8]);
        S1m = __builtin_amdgcn_mfma_f32_16x16x32_f16(qh0, kh1a, S1m, 0, 0, 0);
        S1m = __builtin_amdgcn_mfma_f32_16x16x32_f16(qh1, kh1b, S1m, 0, 0, 0);
        S1c = __builtin_amdgcn_mfma_f32_16x16x32_f16(qh0, kl1a, S1c, 0, 0, 0);
        S1c = __builtin_amdgcn_mfma_f32_16x16x32_f16(qh1, kl1b, S1c, 0, 0, 0);
        S1c = __builtin_amdgcn_mfma_f32_16x16x32_f16(ql0, kh1a, S1c, 0, 0, 0);
        S1c = __builtin_amdgcn_mfma_f32_16x16x32_f16(ql1, kh1b, S1c, 0, 0, 0);
      }
      float S0[4], S1[4];
      int key0 = kt * 32 + m16, key1 = kt * 32 + 16 + m16;
      int am0 = amask ? amask[b * nK + key0] : 1;
      int am1 = amask ? amask[b * nK + key1] : 1;
#pragma unroll
      for (int reg = 0; reg < 4; reg++) {
        int qr = qcbase + reg;
        bool ok0 = am0 && (!causal || key0 <= qr);
        bool ok1 = am1 && (!causal || key1 <= qr);
        S0[reg] = ok0 ? (S0m[reg] + S0c[reg] * ILOSC) * 0.125f : -1e9f;
        S1[reg] = ok1 ? (S1m[reg] + S1c[reg] * ILOSC) * 0.125f : -1e9f;
      }
      float mt[4], al4[4], rs[4];
#pragma unroll
      for (int reg = 0; reg < 4; reg++) mt[reg] = fmaxf(S0[reg], S1[reg]);
#pragma unroll
      for (int off = 1; off < 16; off <<= 1)
#pragma unroll
        for (int reg = 0; reg < 4; reg++) mt[reg] = fmaxf(mt[reg], __shfl_xor(mt[reg], off, 64));
#pragma unroll
      for (int reg = 0; reg < 4; reg++) {
        float mn = fmaxf(mr[reg], mt[reg]);
        al4[reg] = expf(mr[reg] - mn);
        mr[reg] = mn;
        S0[reg] = expf(S0[reg] - mn);
        S1[reg] = expf(S1[reg] - mn);
        rs[reg] = S0[reg] + S1[reg];
      }
#pragma unroll
      for (int off = 1; off < 16; off <<= 1)
#pragma unroll
        for (int reg = 0; reg < 4; reg++) rs[reg] += __shfl_xor(rs[reg], off, 64);
#pragma unroll
      for (int reg = 0; reg < 4; reg++) {
        lrw[reg] = lrw[reg] * al4[reg] + rs[reg];
#pragma unroll
        for (int c = 0; c < 4; c++) { Om[c][reg] *= al4[reg]; Oc[c][reg] *= al4[reg]; }
        int prow = wv * 16 + quad * 4 + reg;
        f16 ph, pl;
        fsplit(S0[reg], ph, pl);
        Psh[prow * 32 + m16] = ph; Psl[prow * 32 + m16] = pl;
        fsplit(S1[reg], ph, pl);
        Psh[prow * 32 + 16 + m16] = ph; Psl[prow * 32 + 16 + m16] = pl;
      }
      __builtin_amdgcn_sched_barrier(0);
      f16x8 pah = *reinterpret_cast<const f16x8*>(&Psh[(wv * 16 + m16) * 32 + quad * 8]);
      f16x8 pal = *reinterpret_cast<const f16x8*>(&Psl[(wv * 16 + m16) * 32 + quad * 8]);
#pragma unroll
      for (int c = 0; c < 4; c++) {
        f16x8 vbh = *reinterpret_cast<const f16x8*>(&Vth[(c * 16 + m16) * 32 + quad * 8]);
        f16x8 vbl = *reinterpret_cast<const f16x8*>(&Vtl[(c * 16 + m16) * 32 + quad * 8]);
        Om[c] = __builtin_amdgcn_mfma_f32_16x16x32_f16(pah, vbh, Om[c], 0, 0, 0);
        Oc[c] = __builtin_amdgcn_mfma_f32_16x16x32_f16(pah, vbl, Oc[c], 0, 0, 0);
        Oc[c] = __builtin_amdgcn_mfma_f32_16x16x32_f16(pal, vbh, Oc[c], 0, 0, 0);
      }
    }
  }
#pragma unroll
  for (int reg = 0; reg < 4; reg++) {
    int qr = qcbase + reg;
    float inv = 1.f / lrw[reg];
#pragma unroll
    for (int c = 0; c < 4; c++) {
      float o = (Om[c][reg] + Oc[c][reg] * ILOSC) * inv;
      f16 hh, ll; fsplit(o, hh, ll);
      size_t oo = (size_t)(b * Tt + qr) * Dd + hd * 64 + c * 16 + m16;
      Oh[oo] = hh;
      Ol[oo] = ll;
    }
  }
}

// ---------------------------------------------------------------------------
__global__ __launch_bounds__(256)
void add_ln_kernel(float* __restrict__ Y, f16* __restrict__ Yh, f16* __restrict__ Yl,
                   const float* __restrict__ Aadd,
                   const float* __restrict__ g, const float* __restrict__ bb) {
  int tid = threadIdx.x;
  size_t base = (size_t)blockIdx.x * Dd;
  __shared__ float red[256];
  __shared__ float mu_s, rs_s;
  float x0 = Y[base + tid] + Aadd[base + tid];
  float x1 = Y[base + 256 + tid] + Aadd[base + 256 + tid];
  red[tid] = x0 + x1; __syncthreads();
  for (int s2 = 128; s2 > 0; s2 >>= 1) { if (tid < s2) red[tid] += red[tid + s2]; __syncthreads(); }
  if (tid == 0) mu_s = red[0] / (float)Dd;
  __syncthreads();
  float mu = mu_s;
  float d0 = x0 - mu, d1 = x1 - mu;
  red[tid] = d0 * d0 + d1 * d1; __syncthreads();
  for (int s2 = 128; s2 > 0; s2 >>= 1) { if (tid < s2) red[tid] += red[tid + s2]; __syncthreads(); }
  if (tid == 0) rs_s = rsqrtf(red[0] / (float)Dd + EPSF);
  __syncthreads();
  float rs = rs_s;
  float o0 = d0 * rs * g[tid] + bb[tid];
  float o1 = d1 * rs * g[256 + tid] + bb[256 + tid];
  f16 h, l;
  Y[base + tid] = o0; fsplit(o0, h, l); Yh[base + tid] = h; Yl[base + tid] = l;
  Y[base + 256 + tid] = o1; fsplit(o1, h, l); Yh[base + 256 + tid] = h; Yl[base + 256 + tid] = l;
}

__global__ __launch_bounds__(256)
void combine_ln_kernel(float* __restrict__ Y, f16* __restrict__ Yh, f16* __restrict__ Yl,
                       const float* __restrict__ pout, const float* __restrict__ pout2,
                       const int* __restrict__ slot,
                       const float* __restrict__ g, const float* __restrict__ bb) {
  int tid = threadIdx.x;
  int m = blockIdx.x;
  size_t base = (size_t)m * Dd;
  int s0 = slot[m * 2 + 0], s1 = slot[m * 2 + 1];
  __shared__ float red[256];
  __shared__ float mu_s, rs_s;
  float x0 = Y[base + tid] + pout[(size_t)s0 * Dd + tid] + pout[(size_t)s1 * Dd + tid]
           + pout2[(size_t)s0 * Dd + tid] + pout2[(size_t)s1 * Dd + tid];
  float x1 = Y[base + 256 + tid] + pout[(size_t)s0 * Dd + 256 + tid] + pout[(size_t)s1 * Dd + 256 + tid]
           + pout2[(size_t)s0 * Dd + 256 + tid] + pout2[(size_t)s1 * Dd + 256 + tid];
  red[tid] = x0 + x1; __syncthreads();
  for (int s2 = 128; s2 > 0; s2 >>= 1) { if (tid < s2) red[tid] += red[tid + s2]; __syncthreads(); }
  if (tid == 0) mu_s = red[0] / (float)Dd;
  __syncthreads();
  float mu = mu_s;
  float d0 = x0 - mu, d1 = x1 - mu;
  red[tid] = d0 * d0 + d1 * d1; __syncthreads();
  for (int s2 = 128; s2 > 0; s2 >>= 1) { if (tid < s2) red[tid] += red[tid + s2]; __syncthreads(); }
  if (tid == 0) rs_s = rsqrtf(red[0] / (float)Dd + EPSF);
  __syncthreads();
  float rs = rs_s;
  float o0 = d0 * rs * g[tid] + bb[tid];
  float o1 = d1 * rs * g[256 + tid] + bb[256 + tid];
  f16 h, l;
  Y[base + tid] = o0; fsplit(o0, h, l); Yh[base + tid] = h; Yl[base + tid] = l;
  Y[base + 256 + tid] = o1; fsplit(o1, h, l); Yh[base + 256 + tid] = h; Yl[base + 256 + tid] = l;
}

// ---------------------------------------------------------------------------
// Router v2: zero contended atomics.
// ---------------------------------------------------------------------------
__global__ __launch_bounds__(256)
void router_kernel(const float* __restrict__ Y, const float* __restrict__ rw,
                   const float* __restrict__ rb, float* __restrict__ gates,
                   int* __restrict__ topi, int* __restrict__ part_cnt,
                   float* __restrict__ part_sumP) {
  int wv = threadIdx.x >> 6, lane = threadIdx.x & 63;
  __shared__ float wsum[4][Ee];
  __shared__ int wcnt[4][Ee];
  float w[8][Ee];
#pragma unroll
  for (int dd = 0; dd < 8; dd++) {
    const float4* rp = reinterpret_cast<const float4*>(&rw[(size_t)(dd * 64 + lane) * Ee]);
    float4 a = rp[0], b4 = rp[1];
    w[dd][0] = a.x; w[dd][1] = a.y; w[dd][2] = a.z; w[dd][3] = a.w;
    w[dd][4] = b4.x; w[dd][5] = b4.y; w[dd][6] = b4.z; w[dd][7] = b4.w;
  }
  float rbv[Ee];
#pragma unroll
  for (int e = 0; e < Ee; e++) rbv[e] = rb[e];

  float psum[Ee]; int pcnt[Ee];
#pragma unroll
  for (int e = 0; e < Ee; e++) { psum[e] = 0.f; pcnt[e] = 0; }

  int m0 = blockIdx.x * 32 + wv * 8;
  for (int j = 0; j < 8; j++) {
    int m = m0 + j;
    const float* yr = Y + (size_t)m * Dd;
    float yv[8];
#pragma unroll
    for (int dd = 0; dd < 8; dd++) yv[dd] = yr[dd * 64 + lane];
    float acc[Ee];
#pragma unroll
    for (int e = 0; e < Ee; e++) acc[e] = 0.f;
#pragma unroll
    for (int dd = 0; dd < 8; dd++)
#pragma unroll
      for (int e = 0; e < Ee; e++) acc[e] += yv[dd] * w[dd][e];
#pragma unroll
    for (int off = 32; off; off >>= 1)
#pragma unroll
      for (int e = 0; e < Ee; e++) acc[e] += __shfl_xor(acc[e], off, 64);
    if (lane == 0) {
      float pv[Ee];
      float mx = -1e30f;
#pragma unroll
      for (int e = 0; e < Ee; e++) { pv[e] = acc[e] + rbv[e]; mx = fmaxf(mx, pv[e]); }
      float ssum = 0.f;
#pragma unroll
      for (int e = 0; e < Ee; e++) { pv[e] = expf(pv[e] - mx); ssum += pv[e]; }
      float invs = 1.f / ssum;
#pragma unroll
      for (int e = 0; e < Ee; e++) { pv[e] *= invs; psum[e] += pv[e]; }
      int i1 = 0;
#pragma unroll
      for (int e = 1; e < Ee; e++) if (pv[e] > pv[i1]) i1 = e;
      int i2 = (i1 == 0) ? 1 : 0;
#pragma unroll
      for (int e = 0; e < Ee; e++) if (e != i1 && pv[e] > pv[i2]) i2 = e;
      float gs = pv[i1] + pv[i2];
      gates[m * 2 + 0] = pv[i1] / gs;
      gates[m * 2 + 1] = pv[i2] / gs;
      topi[m * 2 + 0] = i1;
      topi[m * 2 + 1] = i2;
#pragma unroll
      for (int e = 0; e < Ee; e++) pcnt[e] += (e == i1) + (e == i2);
    }
  }
  if (lane == 0) {
#pragma unroll
    for (int e = 0; e < Ee; e++) { wsum[wv][e] = psum[e]; wcnt[wv][e] = pcnt[e]; }
  }
  __syncthreads();
  if (threadIdx.x < Ee) {
    int e = threadIdx.x;
    float s = wsum[0][e] + wsum[1][e] + wsum[2][e] + wsum[3][e];
    int c = wcnt[0][e] + wcnt[1][e] + wcnt[2][e] + wcnt[3][e];
    part_sumP[blockIdx.x * Ee + e] = s;
    part_cnt[blockIdx.x * Ee + e] = c;
  }
}

__global__ void prefix_lb_kernel(const int* __restrict__ part_cnt,
                                 const float* __restrict__ part_sumP,
                                 int* __restrict__ cnt, int* __restrict__ offs,
                                 int* __restrict__ fill, float* __restrict__ lb_acc) {
  __shared__ int sc[Ee];
  __shared__ float ss[Ee];
  int t = threadIdx.x;
  if (t < Ee) {
    int c = 0; float s = 0.f;
    for (int b2 = 0; b2 < RBLK; b2++) { c += part_cnt[b2 * Ee + t]; s += part_sumP[b2 * Ee + t]; }
    sc[t] = c; ss[t] = s;
    cnt[t] = c; fill[t] = 0;
  }
  __syncthreads();
  if (t == 0) {
    int run = 0;
    float lb = 0.f;
    for (int e = 0; e < Ee; e++) {
      offs[e] = run; run += sc[e];
      lb += ((float)sc[e] * IMm) * (ss[e] * IMm);
    }
    *lb_acc += (float)Ee * lb;
  }
}

__global__ __launch_bounds__(256)
void scatter_kernel(const int* __restrict__ topi, const float* __restrict__ gates,
                    const int* __restrict__ offs, int* __restrict__ fill,
                    int* __restrict__ pair_tok, float* __restrict__ pair_gate,
                    int* __restrict__ slot) {
  __shared__ int lcnt[Ee];
  __shared__ int lbase[Ee];
  int t = threadIdx.x;
  int m = blockIdx.x * 256 + t;
  if (t < Ee) lcnt[t] = 0;
  __syncthreads();
  int e0 = topi[m * 2 + 0], e1 = topi[m * 2 + 1];
  float g0 = gates[m * 2 + 0], g1 = gates[m * 2 + 1];
  int p0 = atomicAdd(&lcnt[e0], 1);
  int p1 = atomicAdd(&lcnt[e1], 1);
  __syncthreads();
  if (t < Ee) lbase[t] = atomicAdd(&fill[t], lcnt[t]);
  __syncthreads();
  int i0 = offs[e0] + lbase[e0] + p0;
  int i1 = offs[e1] + lbase[e1] + p1;
  pair_tok[i0] = m; pair_gate[i0] = g0; slot[m * 2 + 0] = i0;
  pair_tok[i1] = m; pair_gate[i1] = g1; slot[m * 2 + 1] = i1;
}

__global__ void init_lb_kernel(float* lb_acc) {
  if (threadIdx.x == 0) *lb_acc = 0.f;
}

__global__ void finalize_kernel(const float* __restrict__ Y,
                                const float* __restrict__ lb_acc,
                                float* __restrict__ out) {
  size_t i = (size_t)blockIdx.x * 256 + threadIdx.x;
  const size_t n = (size_t)Mm * Dd;
  if (i < n) out[i] = Y[i];
  if (i == 0) out[n] = *lb_acc;
}

// ---------------------------------------------------------------------------
extern "C" void kernel_launch(void* const* d_in, const int* in_sizes, int n_in,
                              void* d_out, int out_size, void* d_ws, size_t ws_size,
                              hipStream_t stream) {
  const int*   ids   = (const int*)d_in[0];
  const float* enc   = (const float*)d_in[1];
  const int*   amask = (const int*)d_in[2];
  const float* emb   = (const float*)d_in[3];
  const float* pos   = (const float*)d_in[4];
  const float* sa_w  = (const float*)d_in[5];
  const float* sa_b  = (const float*)d_in[6];
  const float* ca_w  = (const float*)d_in[7];
  const float* ca_b  = (const float*)d_in[8];
  const float* ln_g  = (const float*)d_in[9];
  const float* ln_b  = (const float*)d_in[10];
  const float* rw    = (const float*)d_in[11];
  const float* rb    = (const float*)d_in[12];
  const float* ew1   = (const float*)d_in[13];
  const float* eb1   = (const float*)d_in[14];
  const float* ew2   = (const float*)d_in[15];
  const float* eb2   = (const float*)d_in[16];
  float* out = (float*)d_out;

  char* p = (char*)d_ws;
  auto alloc = [&](size_t bytes) { void* r = p; p += (bytes + 255) & ~(size_t)255; return r; };
  float* y    = (float*)alloc((size_t)Mm * Dd * 4);
  float* proj = (float*)alloc((size_t)Mm * Dd * 4);
  float* pout = (float*)alloc((size_t)2 * NPp * Dd * 4);   // 2 split-K slices
  f16* yh   = (f16*)alloc((size_t)Mm * Dd * 2);
  f16* yl   = (f16*)alloc((size_t)Mm * Dd * 2);
  f16* ench = (f16*)alloc((size_t)Mm * Dd * 2);
  f16* encl = (f16*)alloc((size_t)Mm * Dd * 2);
  f16* qkvh = (f16*)alloc((size_t)Mm * 1536 * 2);
  f16* qkvl = (f16*)alloc((size_t)Mm * 1536 * 2);
  f16* qch  = (f16*)alloc((size_t)Mm * Dd * 2);
  f16* qcl  = (f16*)alloc((size_t)Mm * Dd * 2);
  f16* atth = (f16*)alloc((size_t)Mm * Dd * 2);
  f16* attl = (f16*)alloc((size_t)Mm * Dd * 2);
  f16* ckvh = (f16*)alloc((size_t)Mm * 1024 * 2);
  f16* ckvl = (f16*)alloc((size_t)Mm * 1024 * 2);
  f16* moeh = (f16*)alloc((size_t)NPp * FFf * 2);
  f16* moel = (f16*)alloc((size_t)NPp * FFf * 2);
  f16* saTh = (f16*)alloc((size_t)Ll * 4 * DD_ * 2);
  f16* saTl = (f16*)alloc((size_t)Ll * 4 * DD_ * 2);
  f16* caTh = (f16*)alloc((size_t)Ll * 4 * DD_ * 2);
  f16* caTl = (f16*)alloc((size_t)Ll * 4 * DD_ * 2);
  f16* w1Th = (f16*)alloc((size_t)Ee * Dd * FFf * 2);
  f16* w1Tl = (f16*)alloc((size_t)Ee * Dd * FFf * 2);
  f16* w2Th = (f16*)alloc((size_t)Ee * Dd * FFf * 2);
  f16* w2Tl = (f16*)alloc((size_t)Ee * Dd * FFf * 2);
  float* gates     = (float*)alloc((size_t)Mm * 2 * 4);
  float* pair_gate = (float*)alloc((size_t)NPp * 4);
  float* part_sumP = (float*)alloc((size_t)RBLK * Ee * 4);
  float* lb_acc    = (float*)alloc(4);
  int* topi     = (int*)alloc((size_t)Mm * 2 * 4);
  int* pair_tok = (int*)alloc((size_t)NPp * 4);
  int* slot     = (int*)alloc((size_t)Mm * 2 * 4);
  int* part_cnt = (int*)alloc((size_t)RBLK * Ee * 4);
  int* cnt      = (int*)alloc(Ee * 4);
  int* offs     = (int*)alloc(Ee * 4);
  int* fill     = (int*)alloc(Ee * 4);
  float* pout2 = pout + (size_t)NPp * Dd;

  init_lb_kernel<<<1, 64, 0, stream>>>(lb_acc);
  embed_kernel<<<Mm, 256, 0, stream>>>(ids, emb, pos, y, yh, yl);
  cvt_split_kernel<<<(Mm * Dd) / 1024, 256, 0, stream>>>(enc, ench, encl);
  transpose_split<<<dim3(16, 16, 16), 256, 0, stream>>>(sa_w, saTh, saTl, Dd, Dd);
  transpose_split<<<dim3(16, 16, 16), 256, 0, stream>>>(ca_w, caTh, caTl, Dd, Dd);

  dim3 gAttn(Bb * Hh, Tt / 64);

  for (int i = 0; i < Ll; i++) {
    transpose_split<<<dim3(64, 16, 8), 256, 0, stream>>>(ew1 + (size_t)i * Ee * Dd * FFf, w1Th, w1Tl, Dd, FFf);
    transpose_split<<<dim3(16, 64, 8), 256, 0, stream>>>(ew2 + (size_t)i * Ee * FFf * Dd, w2Th, w2Tl, FFf, Dd);

    const f16* saThl = saTh + (size_t)i * 4 * DD_;
    const f16* saTll = saTl + (size_t)i * 4 * DD_;
    const f16* caThl = caTh + (size_t)i * 4 * DD_;
    const f16* caTll = caTl + (size_t)i * 4 * DD_;
    const float* sabl = sa_b + (size_t)i * 4 * Dd;
    const float* cabl = ca_b + (size_t)i * 4 * Dd;

    // cross K,V (fused N=1024)
    mm128<false, true, false, false, 1><<<dim3(8, 16, 1), 256, 0, stream>>>(
        ench, encl, Dd, caThl + DD_, caTll + DD_, cabl + Dd,
        nullptr, ckvh, ckvl, 1024, Mm, 1024, Dd, nullptr, nullptr, nullptr, nullptr);
    // self QKV (fused N=1536)
    mm128<false, true, false, false, 1><<<dim3(12, 16, 1), 256, 0, stream>>>(
        yh, yl, Dd, saThl, saTll, sabl,
        nullptr, qkvh, qkvl, 1536, Mm, 1536, Dd, nullptr, nullptr, nullptr, nullptr);
    // self attention
    attn_mfma<<<gAttn, 256, 0, stream>>>(qkvh, qkvl, 1536, 0, qkvh, qkvl, 1536, 512,
                                         qkvh, qkvl, 1536, 1024, atth, attl, amask, 1, Tt);
    // self out-proj
    mm128<false, false, false, false, 1><<<dim3(4, 16, 1), 256, 0, stream>>>(
        atth, attl, Dd, saThl + 3 * DD_, saTll + 3 * DD_, sabl + 3 * Dd,
        proj, nullptr, nullptr, Dd, Mm, Dd, Dd, nullptr, nullptr, nullptr, nullptr);
    add_ln_kernel<<<Mm, 256, 0, stream>>>(y, yh, yl, proj,
                                          ln_g + (size_t)(i * 3 + 0) * Dd, ln_b + (size_t)(i * 3 + 0) * Dd);
    // cross Q
    mm128<false, true, false, false, 1><<<dim3(4, 16, 1), 256, 0, stream>>>(
        yh, yl, Dd, caThl, caTll, cabl,
        nullptr, qch, qcl, Dd, Mm, Dd, Dd, nullptr, nullptr, nullptr, nullptr);
    // cross attention
    attn_mfma<<<gAttn, 256, 0, stream>>>(qch, qcl, Dd, 0, ckvh, ckvl, 1024, 0,
                                         ckvh, ckvl, 1024, 512, atth, attl, nullptr, 0, Ss);
    // cross out-proj
    mm128<false, false, false, false, 1><<<dim3(4, 16, 1), 256, 0, stream>>>(
        atth, attl, Dd, caThl + 3 * DD_, caTll + 3 * DD_, cabl + 3 * Dd,
        proj, nullptr, nullptr, Dd, Mm, Dd, Dd, nullptr, nullptr, nullptr, nullptr);
    add_ln_kernel<<<Mm, 256, 0, stream>>>(y, yh, yl, proj,
                                          ln_g + (size_t)(i * 3 + 1) * Dd, ln_b + (size_t)(i * 3 + 1) * Dd);
    // MoE (atomic-free router)
    router_kernel<<<RBLK, 256, 0, stream>>>(y, rw + (size_t)i * Dd * Ee, rb + (size_t)i * Ee,
                                            gates, topi, part_cnt, part_sumP);
    prefix_lb_kernel<<<1, 64, 0, stream>>>(part_cnt, part_sumP, cnt, offs, fill, lb_acc);
    scatter_kernel<<<Mm / 256, 256, 0, stream>>>(topi, gates, offs, fill, pair_tok, pair_gate, slot);
    mm128<true, true, true, false, 1><<<dim3(16, 32, 8), 256, 0, stream>>>(
        yh, yl, Dd, w1Th, w1Tl, eb1 + (size_t)i * Ee * FFf,
        nullptr, moeh, moel, FFf, NPp, FFf, Dd, pair_tok, nullptr, offs, cnt);
    // w2: split-K x2 via separate output buffers (no atomics)
    mm128<false, false, false, true, 2><<<dim3(4, 32, Ee * 2), 256, 0, stream>>>(
        moeh, moel, FFf, w2Th, w2Tl, eb2 + (size_t)i * Ee * Dd,
        pout, nullptr, nullptr, Dd, NPp, Dd, FFf, nullptr, pair_gate, offs, cnt);
    combine_ln_kernel<<<Mm, 256, 0, stream>>>(y, yh, yl, pout, pout2, slot,
                                              ln_g + (size_t)(i * 3 + 2) * Dd, ln_b + (size_t)(i * 3 + 2) * Dd);
  }

  finalize_kernel<<<(int)(((size_t)Mm * Dd + 256) / 256) + 1, 256, 0, stream>>>(y, lb_acc, out);
}